// Round 10
// baseline (285.134 us; speedup 1.0000x reference)
//
#include <hip/hip_runtime.h>
#include <cstddef>
#include <math.h>

#define L_DIM 2048
#define C_DIM 512
#define CQ_DIM 64
#define B_DIM 8
#define LOG2E 1.44269504088896340736f

typedef _Float16 f16x8 __attribute__((ext_vector_type(8)));
typedef __fp16 fp16x2_t __attribute__((ext_vector_type(2)));
typedef float f32x4 __attribute__((ext_vector_type(4)));

typedef __attribute__((address_space(3))) unsigned int u32_lds;
typedef __attribute__((address_space(1))) const unsigned int u32_glob;

__device__ __forceinline__ unsigned short f2h(float f) {
    union { _Float16 h; unsigned short u; } v;
    v.h = (_Float16)f;
    return v.u;
}

// packed fp32x2 -> fp16x2 (RTZ) as uint
__device__ __forceinline__ unsigned p2u(float a, float b) {
    union { fp16x2_t h; unsigned u; } v;
    v.h = __builtin_amdgcn_cvt_pkrtz(a, b);
    return v.u;
}

// async global->LDS, 16B per lane: LDS dest = wave-uniform base + lane*16
__device__ __forceinline__ void gll16(const unsigned short* g, unsigned short* l) {
    __builtin_amdgcn_global_load_lds((u32_glob*)(const void*)g,
                                     (u32_lds*)(void*)l, 16, 0, 0);
}

// ---------------------------------------------------------------------------
// Fragment-major layouts (producer = conv_all epilogue):
//  qF/kF per b: elem off = (i>>4)*1024 + (c>>5)*512 + ((c>>3)&3)*128 + (i&15)*8 + (c&7)
//  vF per b:    elem off = ((i>>6)*32 + (co>>4))*1024 + ((i>>5)&1)*512
//                          + ((i>>3)&3)*128 + (co&15)*8 + (i&7)
//  A wave's f16x8 MFMA fragment = 16B at (chunk base + lane*16): linear,
//  conflict-free, global_load_lds-verbatim, fully coalesced.
// ---------------------------------------------------------------------------

// ---------------------------------------------------------------------------
// prep_w: Wq/Wk/Wv (fp32 [co][ci][3]) -> Wh fp16 [t][640co][512ci]
// ---------------------------------------------------------------------------
__global__ __launch_bounds__(256) void prep_w(const float* __restrict__ Wq,
                                              const float* __restrict__ Wk,
                                              const float* __restrict__ Wv,
                                              unsigned short* __restrict__ Wh) {
    const int idx = blockIdx.x * 256 + threadIdx.x;
    const int ci = idx & 511;
    const int co = (idx >> 9) % 640;
    const int t  = idx / (640 * 512);
    float w;
    if (co < 64)       w = Wq[(size_t)co * 1536 + ci * 3 + t];
    else if (co < 128) w = Wk[(size_t)(co - 64) * 1536 + ci * 3 + t];
    else               w = Wv[(size_t)(co - 128) * 1536 + ci * 3 + t];
    Wh[idx] = f2h(w);
}

// ---------------------------------------------------------------------------
// prep_x: x fp32 [b][ci][l] -> xT fp16 [b][l][512ci]. 64ci x 64l tile per block.
// ---------------------------------------------------------------------------
__global__ __launch_bounds__(256) void prep_x(const float* __restrict__ x,
                                              unsigned short* __restrict__ xT) {
    const int l0  = blockIdx.x * 64;
    const int ci0 = blockIdx.y * 64;
    const int b   = blockIdx.z;

    __shared__ float xs[64][68];
    const int tid = threadIdx.x;
    const float* xb = x + ((size_t)b * C_DIM + ci0) * L_DIM;

    for (int idx = tid; idx < 64 * 16; idx += 256) {
        int ci = idx >> 4, lq = idx & 15;
        *(float4*)&xs[ci][lq * 4] = *(const float4*)&xb[(size_t)ci * L_DIM + l0 + lq * 4];
    }
    __syncthreads();

    unsigned short* ob = xT + ((size_t)b * L_DIM + l0) * C_DIM + ci0;
    for (int idx = tid; idx < 64 * 8; idx += 256) {
        int l = idx >> 3, c8 = idx & 7;
        ushort4 r0, r1;
        r0.x = f2h(xs[c8 * 8 + 0][l]); r0.y = f2h(xs[c8 * 8 + 1][l]);
        r0.z = f2h(xs[c8 * 8 + 2][l]); r0.w = f2h(xs[c8 * 8 + 3][l]);
        r1.x = f2h(xs[c8 * 8 + 4][l]); r1.y = f2h(xs[c8 * 8 + 5][l]);
        r1.z = f2h(xs[c8 * 8 + 6][l]); r1.w = f2h(xs[c8 * 8 + 7][l]);
        *(ushort4*)&ob[(size_t)l * C_DIM + c8 * 8] = r0;
        *(ushort4*)&ob[(size_t)l * C_DIM + c8 * 8 + 4] = r1;
    }
}

// ---------------------------------------------------------------------------
// conv_all: out[co,l] = sum_t sum_ci Wh[t][co][ci] * x[ci][l+t-1] via MFMA.
// Round-8 proven version: BK=32, reg-staged LDS tiles (26 KB -> high
// occupancy; the r9 3-ring at 63 KB/2-blocks-per-CU was neutral-to-worse:
// per-step compute too thin to hide load latency, TLP lost).
// q output (co0==0) pre-scaled by log2(e). Epilogue: fragment-major q/k/v.
// ---------------------------------------------------------------------------
__global__ __launch_bounds__(256) void conv_all(const unsigned short* __restrict__ Wh,
                                                const unsigned short* __restrict__ xT,
                                                unsigned short* __restrict__ qT,
                                                unsigned short* __restrict__ kT,
                                                unsigned short* __restrict__ vB) {
    const int l0  = blockIdx.x * 128;
    const int co0 = blockIdx.y * 64;
    const int b   = blockIdx.z;

    __shared__ unsigned short As[3][64][40];
    __shared__ unsigned short Bs[130][40];

    const int tid  = threadIdx.x;
    const int lane = tid & 63, w = tid >> 6;
    const int ln15 = lane & 15, quad = lane >> 4;

    const int co_w = (w & 1) * 32;
    const int l_w  = (w >> 1) * 64;

    const unsigned short* xb = xT + (size_t)b * L_DIM * C_DIM;

    f32x4 acc[2][4] = {};

    for (int ci0 = 0; ci0 < C_DIM; ci0 += 32) {
        __syncthreads();
        for (int idx = tid; idx < 768; idx += 256) {
            int t = idx >> 8, co = (idx >> 2) & 63, c8 = idx & 3;
            *(float4*)&As[t][co][c8 * 8] =
                *(const float4*)&Wh[(((size_t)t * 640) + co0 + co) * C_DIM + ci0 + c8 * 8];
        }
        for (int idx = tid; idx < 520; idx += 256) {
            int la = idx >> 2, c8 = idx & 3;
            int l = l0 - 1 + la;
            float4 vx = {0.f, 0.f, 0.f, 0.f};
            if (l >= 0 && l < L_DIM)
                vx = *(const float4*)&xb[(size_t)l * C_DIM + ci0 + c8 * 8];
            *(float4*)&Bs[la][c8 * 8] = vx;
        }
        __syncthreads();

#pragma unroll
        for (int t = 0; t < 3; t++) {
            f16x8 a[2], bfr[4];
#pragma unroll
            for (int ct = 0; ct < 2; ct++)
                a[ct] = *(const f16x8*)&As[t][co_w + ct * 16 + ln15][quad * 8];
#pragma unroll
            for (int lt = 0; lt < 4; lt++)
                bfr[lt] = *(const f16x8*)&Bs[l_w + lt * 16 + ln15 + t][quad * 8];
#pragma unroll
            for (int ct = 0; ct < 2; ct++)
#pragma unroll
                for (int lt = 0; lt < 4; lt++)
                    acc[ct][lt] = __builtin_amdgcn_mfma_f32_16x16x32_f16(a[ct], bfr[lt], acc[ct][lt], 0, 0, 0);
        }
    }

    if (co0 < 128) {
        const float qs = (co0 == 0) ? LOG2E : 1.0f;   // fold log2(e) into q
        unsigned short* dst = (co0 == 0 ? qT : kT) + (size_t)b * L_DIM * CQ_DIM;
#pragma unroll
        for (int ct = 0; ct < 2; ct++)
#pragma unroll
            for (int lt = 0; lt < 4; lt++) {
                const int l = l0 + l_w + lt * 16 + ln15;
                const int c = co_w + ct * 16 + quad * 4;   // 4 consecutive c, same 8-chunk
                ushort4 r;
                r.x = f2h(acc[ct][lt][0] * qs); r.y = f2h(acc[ct][lt][1] * qs);
                r.z = f2h(acc[ct][lt][2] * qs); r.w = f2h(acc[ct][lt][3] * qs);
                const size_t off = (size_t)(l >> 4) * 1024 + (c >> 5) * 512
                                 + (((c >> 3) & 3) * 16 + (l & 15)) * 8 + (c & 7);
                *(ushort4*)&dst[off] = r;
            }
    } else {
        unsigned short* dst = vB + (size_t)b * C_DIM * L_DIM;
#pragma unroll
        for (int ct = 0; ct < 2; ct++)
#pragma unroll
            for (int lt = 0; lt < 4; lt++) {
                const int l = l0 + l_w + lt * 16 + ln15;
                const size_t ibase = ((size_t)(l >> 6) * 32) * 1024 + ((l >> 5) & 1) * 512
                                   + (((l >> 3) & 3) * 16) * 8 + (l & 7);
#pragma unroll
                for (int r = 0; r < 4; r++) {
                    const int vco = (co0 - 128) + co_w + ct * 16 + quad * 4 + r;
                    dst[ibase + (size_t)(vco >> 4) * 1024 + (vco & 15) * 8] = f2h(acc[ct][lt][r]);
                }
            }
    }
}

// ---------------------------------------------------------------------------
// stat_k: per-j softmax stats over an i-chunk of 256, log2 domain.
// Fragment-major q/k read DIRECT from global (coalesced: lane*16B).
// Zero LDS, zero barriers. Grid (8 ich, 32 jb, 8 b) = 2048 blocks.
// ---------------------------------------------------------------------------
__global__ __launch_bounds__(256) void stat_k(const unsigned short* __restrict__ qT,
                                              const unsigned short* __restrict__ kT,
                                              float* __restrict__ pstat) {
    const int ich = blockIdx.x;
    const int j0  = blockIdx.y * 64;
    const int b   = blockIdx.z;

    const int tid = threadIdx.x;
    const int lane = tid & 63, w = tid >> 6;
    const int ln15 = lane & 15, quad = lane >> 4;
    const int sj = w * 16;
    const int lane8 = lane * 8;

    const unsigned short* qb = qT + (size_t)b * L_DIM * CQ_DIM;
    const unsigned short* kb = kT + (size_t)b * L_DIM * CQ_DIM;

    f16x8 kfr[2];
#pragma unroll
    for (int cc = 0; cc < 2; cc++)
        kfr[cc] = *(const f16x8*)&kb[(size_t)((j0 + sj) >> 4) * 1024 + cc * 512 + lane8];

    float m_run = -1e30f, l_run = 0.f;

    for (int t = 0; t < 4; t++) {
        const int ib = ich * 16 + t * 4;   // i-block base (i0>>4)

        f32x4 sacc[4] = {};
#pragma unroll
        for (int cc = 0; cc < 2; cc++) {
#pragma unroll
            for (int it = 0; it < 4; it++) {
                const f16x8 afr = *(const f16x8*)&qb[(size_t)(ib + it) * 1024 + cc * 512 + lane8];
                sacc[it] = __builtin_amdgcn_mfma_f32_16x16x32_f16(afr, kfr[cc], sacc[it], 0, 0, 0);
            }
        }

        float bm = -1e30f;
#pragma unroll
        for (int it = 0; it < 4; it++)
#pragma unroll
            for (int r = 0; r < 4; r++)
                bm = fmaxf(bm, sacc[it][r]);
        bm = fmaxf(bm, __shfl_xor(bm, 16, 64));
        bm = fmaxf(bm, __shfl_xor(bm, 32, 64));
        const float m_new = fmaxf(m_run, bm);
        const float alpha = exp2f(m_run - m_new);

        float lsum = 0.f;
#pragma unroll
        for (int it = 0; it < 4; it++) {
            float p0 = exp2f(sacc[it][0] - m_new);
            float p1 = exp2f(sacc[it][1] - m_new);
            float p2 = exp2f(sacc[it][2] - m_new);
            float p3 = exp2f(sacc[it][3] - m_new);
            lsum += (p0 + p1) + (p2 + p3);
        }
        lsum += __shfl_xor(lsum, 16, 64);
        lsum += __shfl_xor(lsum, 32, 64);
        l_run = l_run * alpha + lsum;
        m_run = m_new;
    }

    if (quad == 0) {
        const int j = j0 + sj + ln15;
        float* pm = pstat;
        float* pl = pstat + 8 * 8 * 2048;
        pm[((size_t)ich * 8 + b) * 2048 + j] = m_run;
        pl[((size_t)ich * 8 + b) * 2048 + j] = l_run;
    }
}

// ---------------------------------------------------------------------------
// pv2: dependency-free PV, exact (m_j,l_j), log2 domain, 2-phase pipeline
// (round-8 proven schedule). CO-SPLIT 8 (64 co per block, grid 32x8x8 = 2048
// blocks): vbuf halves -> LDS ~41.5 KB -> 3 blocks/CU (occ cap 25->37.5%).
// Per-wave staging 4 gll16; oacc 16 VGPR; score work duplicated 8-way but is
// only 8 MFMA + 16 exp2 per iter (no reductions -- stats precomputed).
// ---------------------------------------------------------------------------
__global__ __launch_bounds__(256) void pv2(const unsigned short* __restrict__ qT,
                                           const unsigned short* __restrict__ kT,
                                           const unsigned short* __restrict__ vB,
                                           const float* __restrict__ pstat,
                                           const float* __restrict__ gamma,
                                           float* __restrict__ out) {
    const int j0  = blockIdx.x * 64;
    const int co0 = blockIdx.y * 64;
    const int b   = blockIdx.z;

    __shared__ __align__(16) unsigned short qbuf[2][4096];   // 2 x 8 KB
    __shared__ __align__(16) unsigned short vbuf[2][4096];   // 2 x 8 KB
    __shared__ unsigned short pps[64 * 68];                  // P exchange (padded)
    __shared__ float mj_s[64];
    __shared__ float il_s[64];

    const int tid = threadIdx.x;
    const int lane = tid & 63, w = tid >> 6;
    const int ln15 = lane & 15, quad = lane >> 4;
    const int lane8 = lane * 8;

    const unsigned short* qb = qT + (size_t)b * L_DIM * CQ_DIM;
    const unsigned short* kb = kT + (size_t)b * L_DIM * CQ_DIM;
    const unsigned short* vb = vB + (size_t)b * C_DIM * L_DIM;

    const int sj  = w * 16;   // scores: wave's 16-j group
    const int wco = w * 16;   // PV: wave's co 16-group within 64

    // ---- merge per-chunk stats (log2 domain) ----
    if (tid < 64) {
        const int j = j0 + tid;
        const float* pm = pstat;
        const float* pl = pstat + 8 * 8 * 2048;
        float m = -1e30f;
        float pmv[8];
#pragma unroll
        for (int c = 0; c < 8; c++) {
            pmv[c] = pm[((size_t)c * 8 + b) * 2048 + j];
            m = fmaxf(m, pmv[c]);
        }
        float l = 0.f;
#pragma unroll
        for (int c = 0; c < 8; c++)
            l = fmaf(pl[((size_t)c * 8 + b) * 2048 + j], exp2f(pmv[c] - m), l);
        mj_s[tid] = m;
        il_s[tid] = gamma[0] / l;
    }

    // ---- K fragments direct from global (coalesced, once) ----
    f16x8 kfr[2];
#pragma unroll
    for (int cc = 0; cc < 2; cc++)
        kfr[cc] = *(const f16x8*)&kb[(size_t)((j0 + sj) >> 4) * 1024 + cc * 512 + lane8];

    // ---- prologue: stage tile 0 into buffer 0 ----
    {
        const unsigned short* vsrc = vb + (size_t)(co0 >> 4) * 1024;
#pragma unroll
        for (int s = 0; s < 2; s++)
            gll16(qb + (w * 2 + s) * 512 + lane8, &qbuf[0][(w * 2 + s) * 512]);
#pragma unroll
        for (int s = 0; s < 2; s++)
            gll16(vsrc + (w * 2 + s) * 512 + lane8, &vbuf[0][(w * 2 + s) * 512]);
    }
    __syncthreads();   // drains vmcnt(0) (stage 0 done) + publishes mj_s/il_s

    const float m_lane = mj_s[sj + ln15];
    float inv[4];
#pragma unroll
    for (int bb = 0; bb < 4; bb++)
        inv[bb] = il_s[bb * 16 + ln15];

    f32x4 oacc[4] = {};   // [j-tile]; wave's 16-co group
    int cur = 0;

    for (int i0 = 0; i0 < L_DIM; i0 += 64) {
        // ---- issue next-tile stage (in flight until end-of-iter barrier) ----
        const int i1 = i0 + 64;
        if (i1 < L_DIM) {
            const unsigned short* qsrc = qb + (size_t)(i1 >> 4) * 1024;
            const unsigned short* vsrc = vb + ((size_t)(i1 >> 6) * 32 + (co0 >> 4)) * 1024;
            const int nxt = cur ^ 1;
#pragma unroll
            for (int s = 0; s < 2; s++)
                gll16(qsrc + (w * 2 + s) * 512 + lane8, &qbuf[nxt][(w * 2 + s) * 512]);
#pragma unroll
            for (int s = 0; s < 2; s++)
                gll16(vsrc + (w * 2 + s) * 512 + lane8, &vbuf[nxt][(w * 2 + s) * 512]);
        }

        // ---- scores: S'[64i x 16j] from qbuf[cur] ----
        f32x4 sacc[4] = {};
        __builtin_amdgcn_s_setprio(1);
#pragma unroll
        for (int cc = 0; cc < 2; cc++) {
#pragma unroll
            for (int it = 0; it < 4; it++) {
                const f16x8 afr = *(const f16x8*)&qbuf[cur][(it * 2 + cc) * 512 + lane8];
                sacc[it] = __builtin_amdgcn_mfma_f32_16x16x32_f16(afr, kfr[cc], sacc[it], 0, 0, 0);
            }
        }
        __builtin_amdgcn_s_setprio(0);

        // ---- p = exp2(S' - m'_j) -> pps (this wave's 16 rows) ----
        const int j = sj + ln15;
#pragma unroll
        for (int it = 0; it < 4; it++) {
            float p0 = exp2f(sacc[it][0] - m_lane);
            float p1 = exp2f(sacc[it][1] - m_lane);
            float p2 = exp2f(sacc[it][2] - m_lane);
            float p3 = exp2f(sacc[it][3] - m_lane);
            uint2 u;
            u.x = p2u(p0, p1);
            u.y = p2u(p2, p3);
            *(uint2*)&pps[j * 68 + it * 16 + quad * 4] = u;
        }

        // ---- publish P: raw barrier, lgkm drain only (stage stays in flight) ----
        asm volatile("s_waitcnt lgkmcnt(0)" ::: "memory");
        __builtin_amdgcn_s_barrier();
        __builtin_amdgcn_sched_barrier(0);

        // ---- PV: oacc += V[16co x 64i] * P[64i x 64j] from vbuf[cur] ----
        __builtin_amdgcn_s_setprio(1);
#pragma unroll
        for (int cc = 0; cc < 2; cc++) {
            const f16x8 afr = *(const f16x8*)&vbuf[cur][(w * 2 + cc) * 512 + lane8];
            f16x8 bfr[4];
#pragma unroll
            for (int t = 0; t < 4; t++)
                bfr[t] = *(const f16x8*)&pps[(t * 16 + ln15) * 68 + cc * 32 + quad * 8];
#pragma unroll
            for (int bb = 0; bb < 4; bb++)
                oacc[bb] = __builtin_amdgcn_mfma_f32_16x16x32_f16(afr, bfr[bb], oacc[bb], 0, 0, 0);
        }
        __builtin_amdgcn_s_setprio(0);

        __syncthreads();   // implicit vmcnt(0): next-tile stage complete; all reads done
        cur ^= 1;
    }

    // ---- epilogue: out = oacc * (gamma / l_j) ----
#pragma unroll
    for (int r = 0; r < 4; r++) {
        const int co = co0 + wco + quad * 4 + r;
        float* ob = out + ((size_t)b * C_DIM + co) * L_DIM + j0;
#pragma unroll
        for (int bb = 0; bb < 4; bb++)
            ob[bb * 16 + ln15] = oacc[bb][r] * inv[bb];
    }
}

// ---------------------------------------------------------------------------
extern "C" void kernel_launch(void* const* d_in, const int* in_sizes, int n_in,
                              void* d_out, int out_size, void* d_ws, size_t ws_size,
                              hipStream_t stream) {
    const float* x     = (const float*)d_in[0];
    const float* Wq    = (const float*)d_in[1];
    const float* Wk    = (const float*)d_in[2];
    const float* Wv    = (const float*)d_in[3];
    const float* gamma = (const float*)d_in[4];
    float* out = (float*)d_out;

    unsigned short* ws_h = (unsigned short*)d_ws;
    unsigned short* qT = ws_h;                        // 8*2048*64   = 1,048,576
    unsigned short* kT = qT + 1048576;
    unsigned short* vB = kT + 1048576;                // 8*512*2048  = 8,388,608
    unsigned short* xT = vB + 8388608;                // 8*2048*512  = 8,388,608
    unsigned short* Wh = xT + 8388608;                // 3*640*512   = 983,040
    // stats reuse the xT region (dead after conv_all): 2 * 8*8*2048 floats = 1 MB
    float* pstat = (float*)xT;

    prep_w  <<<3840, 256, 0, stream>>>(Wq, Wk, Wv, Wh);
    prep_x  <<<dim3(32, 8, 8), 256, 0, stream>>>(x, xT);
    conv_all<<<dim3(16, 10, 8), 256, 0, stream>>>(Wh, xT, qT, kT, vB);
    stat_k  <<<dim3(8, 32, 8), 256, 0, stream>>>(qT, kT, pstat);
    pv2     <<<dim3(32, 8, 8), 256, 0, stream>>>(qT, kT, vB, pstat, gamma, out);
}

// Round 11
// 250.174 us; speedup vs baseline: 1.1397x; 1.1397x over previous
//
#include <hip/hip_runtime.h>
#include <cstddef>
#include <math.h>

#define L_DIM 2048
#define C_DIM 512
#define CQ_DIM 64
#define B_DIM 8
#define LOG2E 1.44269504088896340736f

typedef _Float16 f16x8 __attribute__((ext_vector_type(8)));
typedef __fp16 fp16x2_t __attribute__((ext_vector_type(2)));
typedef float f32x4 __attribute__((ext_vector_type(4)));

typedef __attribute__((address_space(3))) unsigned int u32_lds;
typedef __attribute__((address_space(1))) const unsigned int u32_glob;

__device__ __forceinline__ unsigned short f2h(float f) {
    union { _Float16 h; unsigned short u; } v;
    v.h = (_Float16)f;
    return v.u;
}

// packed fp32x2 -> fp16x2 (RTZ) as uint
__device__ __forceinline__ unsigned p2u(float a, float b) {
    union { fp16x2_t h; unsigned u; } v;
    v.h = __builtin_amdgcn_cvt_pkrtz(a, b);
    return v.u;
}

// async global->LDS, 16B per lane: LDS dest = wave-uniform base + lane*16
__device__ __forceinline__ void gll16(const unsigned short* g, unsigned short* l) {
    __builtin_amdgcn_global_load_lds((u32_glob*)(const void*)g,
                                     (u32_lds*)(void*)l, 16, 0, 0);
}

// ---------------------------------------------------------------------------
// Fragment-major layouts (producer = conv_all epilogue):
//  qF/kF per b: elem off = (i>>4)*1024 + (c>>5)*512 + ((c>>3)&3)*128 + (i&15)*8 + (c&7)
//  vF per b:    elem off = ((i>>6)*32 + (co>>4))*1024 + ((i>>5)&1)*512
//                          + ((i>>3)&3)*128 + (co&15)*8 + (i&7)
//  A wave's f16x8 MFMA fragment = 16B at (chunk base + lane*16): linear,
//  conflict-free, global_load_lds-verbatim, fully coalesced.
// ---------------------------------------------------------------------------

// ---------------------------------------------------------------------------
// prep_w: Wq/Wk/Wv (fp32 [co][ci][3]) -> Wh fp16 [t][640co][512ci]
// ---------------------------------------------------------------------------
__global__ __launch_bounds__(256) void prep_w(const float* __restrict__ Wq,
                                              const float* __restrict__ Wk,
                                              const float* __restrict__ Wv,
                                              unsigned short* __restrict__ Wh) {
    const int idx = blockIdx.x * 256 + threadIdx.x;
    const int ci = idx & 511;
    const int co = (idx >> 9) % 640;
    const int t  = idx / (640 * 512);
    float w;
    if (co < 64)       w = Wq[(size_t)co * 1536 + ci * 3 + t];
    else if (co < 128) w = Wk[(size_t)(co - 64) * 1536 + ci * 3 + t];
    else               w = Wv[(size_t)(co - 128) * 1536 + ci * 3 + t];
    Wh[idx] = f2h(w);
}

// ---------------------------------------------------------------------------
// prep_x: x fp32 [b][ci][l] -> xT fp16 [b][l][512ci]. 64ci x 64l tile per block.
// ---------------------------------------------------------------------------
__global__ __launch_bounds__(256) void prep_x(const float* __restrict__ x,
                                              unsigned short* __restrict__ xT) {
    const int l0  = blockIdx.x * 64;
    const int ci0 = blockIdx.y * 64;
    const int b   = blockIdx.z;

    __shared__ float xs[64][68];
    const int tid = threadIdx.x;
    const float* xb = x + ((size_t)b * C_DIM + ci0) * L_DIM;

    for (int idx = tid; idx < 64 * 16; idx += 256) {
        int ci = idx >> 4, lq = idx & 15;
        *(float4*)&xs[ci][lq * 4] = *(const float4*)&xb[(size_t)ci * L_DIM + l0 + lq * 4];
    }
    __syncthreads();

    unsigned short* ob = xT + ((size_t)b * L_DIM + l0) * C_DIM + ci0;
    for (int idx = tid; idx < 64 * 8; idx += 256) {
        int l = idx >> 3, c8 = idx & 7;
        ushort4 r0, r1;
        r0.x = f2h(xs[c8 * 8 + 0][l]); r0.y = f2h(xs[c8 * 8 + 1][l]);
        r0.z = f2h(xs[c8 * 8 + 2][l]); r0.w = f2h(xs[c8 * 8 + 3][l]);
        r1.x = f2h(xs[c8 * 8 + 4][l]); r1.y = f2h(xs[c8 * 8 + 5][l]);
        r1.z = f2h(xs[c8 * 8 + 6][l]); r1.w = f2h(xs[c8 * 8 + 7][l]);
        *(ushort4*)&ob[(size_t)l * C_DIM + c8 * 8] = r0;
        *(ushort4*)&ob[(size_t)l * C_DIM + c8 * 8 + 4] = r1;
    }
}

// ---------------------------------------------------------------------------
// conv_all: out[co,l] = sum_t sum_ci Wh[t][co][ci] * x[ci][l+t-1] via MFMA.
// Round-8 proven version: BK=32, reg-staged LDS tiles (26 KB -> high
// occupancy). The r9 3-ring (63 KB, 2 blocks/CU) was neutral-to-worse:
// per-step compute too thin to hide load latency; TLP was doing the hiding.
// q output (co0==0) pre-scaled by log2(e). Epilogue: fragment-major q/k/v.
// ---------------------------------------------------------------------------
__global__ __launch_bounds__(256) void conv_all(const unsigned short* __restrict__ Wh,
                                                const unsigned short* __restrict__ xT,
                                                unsigned short* __restrict__ qT,
                                                unsigned short* __restrict__ kT,
                                                unsigned short* __restrict__ vB) {
    const int l0  = blockIdx.x * 128;
    const int co0 = blockIdx.y * 64;
    const int b   = blockIdx.z;

    __shared__ unsigned short As[3][64][40];
    __shared__ unsigned short Bs[130][40];

    const int tid  = threadIdx.x;
    const int lane = tid & 63, w = tid >> 6;
    const int ln15 = lane & 15, quad = lane >> 4;

    const int co_w = (w & 1) * 32;
    const int l_w  = (w >> 1) * 64;

    const unsigned short* xb = xT + (size_t)b * L_DIM * C_DIM;

    f32x4 acc[2][4] = {};

    for (int ci0 = 0; ci0 < C_DIM; ci0 += 32) {
        __syncthreads();
        for (int idx = tid; idx < 768; idx += 256) {
            int t = idx >> 8, co = (idx >> 2) & 63, c8 = idx & 3;
            *(float4*)&As[t][co][c8 * 8] =
                *(const float4*)&Wh[(((size_t)t * 640) + co0 + co) * C_DIM + ci0 + c8 * 8];
        }
        for (int idx = tid; idx < 520; idx += 256) {
            int la = idx >> 2, c8 = idx & 3;
            int l = l0 - 1 + la;
            float4 vx = {0.f, 0.f, 0.f, 0.f};
            if (l >= 0 && l < L_DIM)
                vx = *(const float4*)&xb[(size_t)l * C_DIM + ci0 + c8 * 8];
            *(float4*)&Bs[la][c8 * 8] = vx;
        }
        __syncthreads();

#pragma unroll
        for (int t = 0; t < 3; t++) {
            f16x8 a[2], bfr[4];
#pragma unroll
            for (int ct = 0; ct < 2; ct++)
                a[ct] = *(const f16x8*)&As[t][co_w + ct * 16 + ln15][quad * 8];
#pragma unroll
            for (int lt = 0; lt < 4; lt++)
                bfr[lt] = *(const f16x8*)&Bs[l_w + lt * 16 + ln15 + t][quad * 8];
#pragma unroll
            for (int ct = 0; ct < 2; ct++)
#pragma unroll
                for (int lt = 0; lt < 4; lt++)
                    acc[ct][lt] = __builtin_amdgcn_mfma_f32_16x16x32_f16(a[ct], bfr[lt], acc[ct][lt], 0, 0, 0);
        }
    }

    if (co0 < 128) {
        const float qs = (co0 == 0) ? LOG2E : 1.0f;   // fold log2(e) into q
        unsigned short* dst = (co0 == 0 ? qT : kT) + (size_t)b * L_DIM * CQ_DIM;
#pragma unroll
        for (int ct = 0; ct < 2; ct++)
#pragma unroll
            for (int lt = 0; lt < 4; lt++) {
                const int l = l0 + l_w + lt * 16 + ln15;
                const int c = co_w + ct * 16 + quad * 4;   // 4 consecutive c, same 8-chunk
                ushort4 r;
                r.x = f2h(acc[ct][lt][0] * qs); r.y = f2h(acc[ct][lt][1] * qs);
                r.z = f2h(acc[ct][lt][2] * qs); r.w = f2h(acc[ct][lt][3] * qs);
                const size_t off = (size_t)(l >> 4) * 1024 + (c >> 5) * 512
                                 + (((c >> 3) & 3) * 16 + (l & 15)) * 8 + (c & 7);
                *(ushort4*)&dst[off] = r;
            }
    } else {
        unsigned short* dst = vB + (size_t)b * C_DIM * L_DIM;
#pragma unroll
        for (int ct = 0; ct < 2; ct++)
#pragma unroll
            for (int lt = 0; lt < 4; lt++) {
                const int l = l0 + l_w + lt * 16 + ln15;
                const size_t ibase = ((size_t)(l >> 6) * 32) * 1024 + ((l >> 5) & 1) * 512
                                   + (((l >> 3) & 3) * 16) * 8 + (l & 7);
#pragma unroll
                for (int r = 0; r < 4; r++) {
                    const int vco = (co0 - 128) + co_w + ct * 16 + quad * 4 + r;
                    dst[ibase + (size_t)(vco >> 4) * 1024 + (vco & 15) * 8] = f2h(acc[ct][lt][r]);
                }
            }
    }
}

// ---------------------------------------------------------------------------
// stat_k: per-j softmax stats over an i-chunk of 256, log2 domain.
// Fragment-major q/k read DIRECT from global (coalesced: lane*16B).
// Zero LDS, zero barriers. Grid (8 ich, 32 jb, 8 b) = 2048 blocks.
// ---------------------------------------------------------------------------
__global__ __launch_bounds__(256) void stat_k(const unsigned short* __restrict__ qT,
                                              const unsigned short* __restrict__ kT,
                                              float* __restrict__ pstat) {
    const int ich = blockIdx.x;
    const int j0  = blockIdx.y * 64;
    const int b   = blockIdx.z;

    const int tid = threadIdx.x;
    const int lane = tid & 63, w = tid >> 6;
    const int ln15 = lane & 15, quad = lane >> 4;
    const int sj = w * 16;
    const int lane8 = lane * 8;

    const unsigned short* qb = qT + (size_t)b * L_DIM * CQ_DIM;
    const unsigned short* kb = kT + (size_t)b * L_DIM * CQ_DIM;

    f16x8 kfr[2];
#pragma unroll
    for (int cc = 0; cc < 2; cc++)
        kfr[cc] = *(const f16x8*)&kb[(size_t)((j0 + sj) >> 4) * 1024 + cc * 512 + lane8];

    float m_run = -1e30f, l_run = 0.f;

    for (int t = 0; t < 4; t++) {
        const int ib = ich * 16 + t * 4;   // i-block base (i0>>4)

        f32x4 sacc[4] = {};
#pragma unroll
        for (int cc = 0; cc < 2; cc++) {
#pragma unroll
            for (int it = 0; it < 4; it++) {
                const f16x8 afr = *(const f16x8*)&qb[(size_t)(ib + it) * 1024 + cc * 512 + lane8];
                sacc[it] = __builtin_amdgcn_mfma_f32_16x16x32_f16(afr, kfr[cc], sacc[it], 0, 0, 0);
            }
        }

        float bm = -1e30f;
#pragma unroll
        for (int it = 0; it < 4; it++)
#pragma unroll
            for (int r = 0; r < 4; r++)
                bm = fmaxf(bm, sacc[it][r]);
        bm = fmaxf(bm, __shfl_xor(bm, 16, 64));
        bm = fmaxf(bm, __shfl_xor(bm, 32, 64));
        const float m_new = fmaxf(m_run, bm);
        const float alpha = exp2f(m_run - m_new);

        float lsum = 0.f;
#pragma unroll
        for (int it = 0; it < 4; it++) {
            float p0 = exp2f(sacc[it][0] - m_new);
            float p1 = exp2f(sacc[it][1] - m_new);
            float p2 = exp2f(sacc[it][2] - m_new);
            float p3 = exp2f(sacc[it][3] - m_new);
            lsum += (p0 + p1) + (p2 + p3);
        }
        lsum += __shfl_xor(lsum, 16, 64);
        lsum += __shfl_xor(lsum, 32, 64);
        l_run = l_run * alpha + lsum;
        m_run = m_new;
    }

    if (quad == 0) {
        const int j = j0 + sj + ln15;
        float* pm = pstat;
        float* pl = pstat + 8 * 8 * 2048;
        pm[((size_t)ich * 8 + b) * 2048 + j] = m_run;
        pl[((size_t)ich * 8 + b) * 2048 + j] = l_run;
    }
}

// ---------------------------------------------------------------------------
// pv2: dependency-free PV, exact (m_j,l_j), log2 domain, 2-phase pipeline.
// Round-8 proven configuration (co-split 4, 128 co/block, grid 32x4x8):
// the measured optimum across six structural probes (split-8 = VALU-bound on
// duplicated exp2; wave-owned-j = +LDS traffic; de-staged = latency-bound;
// reg-prefetch = spill; ring-3 = occupancy loss). Double-buffered LDS filled
// by gll16 (zero-VGPR staging), next-tile stage in flight across the whole
// iter, drained at the end-of-iter __syncthreads; mid-iter P-publish uses a
// raw s_barrier + lgkmcnt(0) only. Micro-tweak vs r8: prologue stage issued
// FIRST so its flight time overlaps the stats-merge VALU work.
// ---------------------------------------------------------------------------
__global__ __launch_bounds__(256) void pv2(const unsigned short* __restrict__ qT,
                                           const unsigned short* __restrict__ kT,
                                           const unsigned short* __restrict__ vB,
                                           const float* __restrict__ pstat,
                                           const float* __restrict__ gamma,
                                           float* __restrict__ out) {
    const int j0  = blockIdx.x * 64;
    const int co0 = blockIdx.y * 128;
    const int b   = blockIdx.z;

    __shared__ __align__(16) unsigned short qbuf[2][4096];   // 2 x 8 KB
    __shared__ __align__(16) unsigned short vbuf[2][8192];   // 2 x 16 KB
    __shared__ unsigned short pps[64 * 68];                  // P exchange (padded)
    __shared__ float mj_s[64];
    __shared__ float il_s[64];

    const int tid = threadIdx.x;
    const int lane = tid & 63, w = tid >> 6;
    const int ln15 = lane & 15, quad = lane >> 4;
    const int lane8 = lane * 8;

    const unsigned short* qb = qT + (size_t)b * L_DIM * CQ_DIM;
    const unsigned short* kb = kT + (size_t)b * L_DIM * CQ_DIM;
    const unsigned short* vb = vB + (size_t)b * C_DIM * L_DIM;

    const int sj  = w * 16;   // scores: wave's 16-j group
    const int wco = w * 32;   // PV: wave's co group within 128

    // ---- prologue: stage tile 0 into buffer 0 (async; overlaps stats merge) ----
    {
        const unsigned short* vsrc = vb + (size_t)(co0 >> 4) * 1024;
#pragma unroll
        for (int s = 0; s < 2; s++)
            gll16(qb + (w * 2 + s) * 512 + lane8, &qbuf[0][(w * 2 + s) * 512]);
#pragma unroll
        for (int s = 0; s < 4; s++)
            gll16(vsrc + (w * 4 + s) * 512 + lane8, &vbuf[0][(w * 4 + s) * 512]);
    }

    // ---- merge per-chunk stats (log2 domain) under the stage's flight ----
    if (tid < 64) {
        const int j = j0 + tid;
        const float* pm = pstat;
        const float* pl = pstat + 8 * 8 * 2048;
        float m = -1e30f;
        float pmv[8];
#pragma unroll
        for (int c = 0; c < 8; c++) {
            pmv[c] = pm[((size_t)c * 8 + b) * 2048 + j];
            m = fmaxf(m, pmv[c]);
        }
        float l = 0.f;
#pragma unroll
        for (int c = 0; c < 8; c++)
            l = fmaf(pl[((size_t)c * 8 + b) * 2048 + j], exp2f(pmv[c] - m), l);
        mj_s[tid] = m;
        il_s[tid] = gamma[0] / l;
    }

    // ---- K fragments direct from global (coalesced, once) ----
    f16x8 kfr[2];
#pragma unroll
    for (int cc = 0; cc < 2; cc++)
        kfr[cc] = *(const f16x8*)&kb[(size_t)((j0 + sj) >> 4) * 1024 + cc * 512 + lane8];

    __syncthreads();   // drains vmcnt(0) (stage 0 done) + publishes mj_s/il_s

    const float m_lane = mj_s[sj + ln15];
    float inv[4];
#pragma unroll
    for (int bb = 0; bb < 4; bb++)
        inv[bb] = il_s[bb * 16 + ln15];

    f32x4 oacc[2][4] = {};   // [co-tile][j-tile]
    int cur = 0;

    for (int i0 = 0; i0 < L_DIM; i0 += 64) {
        // ---- issue next-tile stage (in flight until end-of-iter barrier) ----
        const int i1 = i0 + 64;
        if (i1 < L_DIM) {
            const unsigned short* qsrc = qb + (size_t)(i1 >> 4) * 1024;
            const unsigned short* vsrc = vb + ((size_t)(i1 >> 6) * 32 + (co0 >> 4)) * 1024;
            const int nxt = cur ^ 1;
#pragma unroll
            for (int s = 0; s < 2; s++)
                gll16(qsrc + (w * 2 + s) * 512 + lane8, &qbuf[nxt][(w * 2 + s) * 512]);
#pragma unroll
            for (int s = 0; s < 4; s++)
                gll16(vsrc + (w * 4 + s) * 512 + lane8, &vbuf[nxt][(w * 4 + s) * 512]);
        }

        // ---- scores: S'[64i x 16j] from qbuf[cur] ----
        f32x4 sacc[4] = {};
        __builtin_amdgcn_s_setprio(1);
#pragma unroll
        for (int cc = 0; cc < 2; cc++) {
#pragma unroll
            for (int it = 0; it < 4; it++) {
                const f16x8 afr = *(const f16x8*)&qbuf[cur][(it * 2 + cc) * 512 + lane8];
                sacc[it] = __builtin_amdgcn_mfma_f32_16x16x32_f16(afr, kfr[cc], sacc[it], 0, 0, 0);
            }
        }
        __builtin_amdgcn_s_setprio(0);

        // ---- p = exp2(S' - m'_j) -> pps (this wave's 16 rows) ----
        const int j = sj + ln15;
#pragma unroll
        for (int it = 0; it < 4; it++) {
            float p0 = exp2f(sacc[it][0] - m_lane);
            float p1 = exp2f(sacc[it][1] - m_lane);
            float p2 = exp2f(sacc[it][2] - m_lane);
            float p3 = exp2f(sacc[it][3] - m_lane);
            uint2 u;
            u.x = p2u(p0, p1);
            u.y = p2u(p2, p3);
            *(uint2*)&pps[j * 68 + it * 16 + quad * 4] = u;
        }

        // ---- publish P: raw barrier, lgkm drain only (stage stays in flight) ----
        asm volatile("s_waitcnt lgkmcnt(0)" ::: "memory");
        __builtin_amdgcn_s_barrier();
        __builtin_amdgcn_sched_barrier(0);

        // ---- PV: oacc += V[32co x 64i] * P[64i x 64j] from vbuf[cur] ----
        __builtin_amdgcn_s_setprio(1);
#pragma unroll
        for (int cc = 0; cc < 2; cc++) {
            f16x8 afr[2], bfr[4];
#pragma unroll
            for (int t = 0; t < 2; t++)
                afr[t] = *(const f16x8*)&vbuf[cur][((w * 2 + t) * 2 + cc) * 512 + lane8];
#pragma unroll
            for (int t = 0; t < 4; t++)
                bfr[t] = *(const f16x8*)&pps[(t * 16 + ln15) * 68 + cc * 32 + quad * 8];
#pragma unroll
            for (int a = 0; a < 2; a++)
#pragma unroll
                for (int bb = 0; bb < 4; bb++)
                    oacc[a][bb] = __builtin_amdgcn_mfma_f32_16x16x32_f16(afr[a], bfr[bb], oacc[a][bb], 0, 0, 0);
        }
        __builtin_amdgcn_s_setprio(0);

        __syncthreads();   // implicit vmcnt(0): next-tile stage complete; all reads done
        cur ^= 1;
    }

    // ---- epilogue: out = oacc * (gamma / l_j) ----
#pragma unroll
    for (int a = 0; a < 2; a++)
#pragma unroll
        for (int r = 0; r < 4; r++) {
            const int co = co0 + wco + a * 16 + quad * 4 + r;
            float* ob = out + ((size_t)b * C_DIM + co) * L_DIM + j0;
#pragma unroll
            for (int bb = 0; bb < 4; bb++)
                ob[bb * 16 + ln15] = oacc[a][bb][r] * inv[bb];
        }
}

// ---------------------------------------------------------------------------
extern "C" void kernel_launch(void* const* d_in, const int* in_sizes, int n_in,
                              void* d_out, int out_size, void* d_ws, size_t ws_size,
                              hipStream_t stream) {
    const float* x     = (const float*)d_in[0];
    const float* Wq    = (const float*)d_in[1];
    const float* Wk    = (const float*)d_in[2];
    const float* Wv    = (const float*)d_in[3];
    const float* gamma = (const float*)d_in[4];
    float* out = (float*)d_out;

    unsigned short* ws_h = (unsigned short*)d_ws;
    unsigned short* qT = ws_h;                        // 8*2048*64   = 1,048,576
    unsigned short* kT = qT + 1048576;
    unsigned short* vB = kT + 1048576;                // 8*512*2048  = 8,388,608
    unsigned short* xT = vB + 8388608;                // 8*2048*512  = 8,388,608
    unsigned short* Wh = xT + 8388608;                // 3*640*512   = 983,040
    // stats reuse the xT region (dead after conv_all): 2 * 8*8*2048 floats = 1 MB
    float* pstat = (float*)xT;

    prep_w  <<<3840, 256, 0, stream>>>(Wq, Wk, Wv, Wh);
    prep_x  <<<dim3(32, 8, 8), 256, 0, stream>>>(x, xT);
    conv_all<<<dim3(16, 10, 8), 256, 0, stream>>>(Wh, xT, qT, kT, vB);
    stat_k  <<<dim3(8, 32, 8), 256, 0, stream>>>(qT, kT, pstat);
    pv2     <<<dim3(32, 4, 8), 256, 0, stream>>>(qT, kT, vB, pstat, gamma, out);
}

// Round 12
// 230.222 us; speedup vs baseline: 1.2385x; 1.0867x over previous
//
#include <hip/hip_runtime.h>
#include <cstddef>
#include <math.h>

#define L_DIM 2048
#define C_DIM 512
#define CQ_DIM 64
#define B_DIM 8
#define LOG2E 1.44269504088896340736f

typedef _Float16 f16x8 __attribute__((ext_vector_type(8)));
typedef __fp16 fp16x2_t __attribute__((ext_vector_type(2)));
typedef float f32x4 __attribute__((ext_vector_type(4)));

typedef __attribute__((address_space(3))) unsigned int u32_lds;
typedef __attribute__((address_space(1))) const unsigned int u32_glob;

__device__ __forceinline__ unsigned short f2h(float f) {
    union { _Float16 h; unsigned short u; } v;
    v.h = (_Float16)f;
    return v.u;
}

// packed fp32x2 -> fp16x2 (RTZ) as uint
__device__ __forceinline__ unsigned p2u(float a, float b) {
    union { fp16x2_t h; unsigned u; } v;
    v.h = __builtin_amdgcn_cvt_pkrtz(a, b);
    return v.u;
}

// async global->LDS, 16B per lane: LDS dest = wave-uniform base + lane*16
__device__ __forceinline__ void gll16(const unsigned short* g, unsigned short* l) {
    __builtin_amdgcn_global_load_lds((u32_glob*)(const void*)g,
                                     (u32_lds*)(void*)l, 16, 0, 0);
}

// ---------------------------------------------------------------------------
// Fragment-major layouts (producer-controlled):
//  qF/kF per b: elem off = (i>>4)*1024 + (c>>5)*512 + ((c>>3)&3)*128 + (i&15)*8 + (c&7)
//  vF per b:    elem off = ((i>>6)*32 + (co>>4))*1024 + ((i>>5)&1)*512
//                          + ((i>>3)&3)*128 + (co&15)*8 + (i&7)
//  P  per b:    elem off = ((j>>4)*64 + (i>>5))*512 + ((i>>3)&3)*128 + (j&15)*8 + (i&7)
//  A wave's f16x8 MFMA fragment = 16B at (chunk base + lane*16): linear,
//  conflict-free, global_load_lds-verbatim, fully coalesced.
// ---------------------------------------------------------------------------

// ---------------------------------------------------------------------------
// prep_w: Wq/Wk/Wv (fp32 [co][ci][3]) -> Wh fp16 [t][640co][512ci]
// ---------------------------------------------------------------------------
__global__ __launch_bounds__(256) void prep_w(const float* __restrict__ Wq,
                                              const float* __restrict__ Wk,
                                              const float* __restrict__ Wv,
                                              unsigned short* __restrict__ Wh) {
    const int idx = blockIdx.x * 256 + threadIdx.x;
    const int ci = idx & 511;
    const int co = (idx >> 9) % 640;
    const int t  = idx / (640 * 512);
    float w;
    if (co < 64)       w = Wq[(size_t)co * 1536 + ci * 3 + t];
    else if (co < 128) w = Wk[(size_t)(co - 64) * 1536 + ci * 3 + t];
    else               w = Wv[(size_t)(co - 128) * 1536 + ci * 3 + t];
    Wh[idx] = f2h(w);
}

// ---------------------------------------------------------------------------
// prep_x: x fp32 [b][ci][l] -> xT fp16 [b][l][512ci]. 64ci x 64l tile per block.
// ---------------------------------------------------------------------------
__global__ __launch_bounds__(256) void prep_x(const float* __restrict__ x,
                                              unsigned short* __restrict__ xT) {
    const int l0  = blockIdx.x * 64;
    const int ci0 = blockIdx.y * 64;
    const int b   = blockIdx.z;

    __shared__ float xs[64][68];
    const int tid = threadIdx.x;
    const float* xb = x + ((size_t)b * C_DIM + ci0) * L_DIM;

    for (int idx = tid; idx < 64 * 16; idx += 256) {
        int ci = idx >> 4, lq = idx & 15;
        *(float4*)&xs[ci][lq * 4] = *(const float4*)&xb[(size_t)ci * L_DIM + l0 + lq * 4];
    }
    __syncthreads();

    unsigned short* ob = xT + ((size_t)b * L_DIM + l0) * C_DIM + ci0;
    for (int idx = tid; idx < 64 * 8; idx += 256) {
        int l = idx >> 3, c8 = idx & 7;
        ushort4 r0, r1;
        r0.x = f2h(xs[c8 * 8 + 0][l]); r0.y = f2h(xs[c8 * 8 + 1][l]);
        r0.z = f2h(xs[c8 * 8 + 2][l]); r0.w = f2h(xs[c8 * 8 + 3][l]);
        r1.x = f2h(xs[c8 * 8 + 4][l]); r1.y = f2h(xs[c8 * 8 + 5][l]);
        r1.z = f2h(xs[c8 * 8 + 6][l]); r1.w = f2h(xs[c8 * 8 + 7][l]);
        *(ushort4*)&ob[(size_t)l * C_DIM + c8 * 8] = r0;
        *(ushort4*)&ob[(size_t)l * C_DIM + c8 * 8 + 4] = r1;
    }
}

// ---------------------------------------------------------------------------
// conv_all: out[co,l] = sum_t sum_ci Wh[t][co][ci] * x[ci][l+t-1] via MFMA.
// Round-8 proven version: BK=32, reg-staged LDS tiles (26 KB -> high occ).
// q output (co0==0) pre-scaled by log2(e). Epilogue: fragment-major q/k/v.
// ---------------------------------------------------------------------------
__global__ __launch_bounds__(256) void conv_all(const unsigned short* __restrict__ Wh,
                                                const unsigned short* __restrict__ xT,
                                                unsigned short* __restrict__ qT,
                                                unsigned short* __restrict__ kT,
                                                unsigned short* __restrict__ vB) {
    const int l0  = blockIdx.x * 128;
    const int co0 = blockIdx.y * 64;
    const int b   = blockIdx.z;

    __shared__ unsigned short As[3][64][40];
    __shared__ unsigned short Bs[130][40];

    const int tid  = threadIdx.x;
    const int lane = tid & 63, w = tid >> 6;
    const int ln15 = lane & 15, quad = lane >> 4;

    const int co_w = (w & 1) * 32;
    const int l_w  = (w >> 1) * 64;

    const unsigned short* xb = xT + (size_t)b * L_DIM * C_DIM;

    f32x4 acc[2][4] = {};

    for (int ci0 = 0; ci0 < C_DIM; ci0 += 32) {
        __syncthreads();
        for (int idx = tid; idx < 768; idx += 256) {
            int t = idx >> 8, co = (idx >> 2) & 63, c8 = idx & 3;
            *(float4*)&As[t][co][c8 * 8] =
                *(const float4*)&Wh[(((size_t)t * 640) + co0 + co) * C_DIM + ci0 + c8 * 8];
        }
        for (int idx = tid; idx < 520; idx += 256) {
            int la = idx >> 2, c8 = idx & 3;
            int l = l0 - 1 + la;
            float4 vx = {0.f, 0.f, 0.f, 0.f};
            if (l >= 0 && l < L_DIM)
                vx = *(const float4*)&xb[(size_t)l * C_DIM + ci0 + c8 * 8];
            *(float4*)&Bs[la][c8 * 8] = vx;
        }
        __syncthreads();

#pragma unroll
        for (int t = 0; t < 3; t++) {
            f16x8 a[2], bfr[4];
#pragma unroll
            for (int ct = 0; ct < 2; ct++)
                a[ct] = *(const f16x8*)&As[t][co_w + ct * 16 + ln15][quad * 8];
#pragma unroll
            for (int lt = 0; lt < 4; lt++)
                bfr[lt] = *(const f16x8*)&Bs[l_w + lt * 16 + ln15 + t][quad * 8];
#pragma unroll
            for (int ct = 0; ct < 2; ct++)
#pragma unroll
                for (int lt = 0; lt < 4; lt++)
                    acc[ct][lt] = __builtin_amdgcn_mfma_f32_16x16x32_f16(a[ct], bfr[lt], acc[ct][lt], 0, 0, 0);
        }
    }

    if (co0 < 128) {
        const float qs = (co0 == 0) ? LOG2E : 1.0f;   // fold log2(e) into q
        unsigned short* dst = (co0 == 0 ? qT : kT) + (size_t)b * L_DIM * CQ_DIM;
#pragma unroll
        for (int ct = 0; ct < 2; ct++)
#pragma unroll
            for (int lt = 0; lt < 4; lt++) {
                const int l = l0 + l_w + lt * 16 + ln15;
                const int c = co_w + ct * 16 + quad * 4;   // 4 consecutive c, same 8-chunk
                ushort4 r;
                r.x = f2h(acc[ct][lt][0] * qs); r.y = f2h(acc[ct][lt][1] * qs);
                r.z = f2h(acc[ct][lt][2] * qs); r.w = f2h(acc[ct][lt][3] * qs);
                const size_t off = (size_t)(l >> 4) * 1024 + (c >> 5) * 512
                                 + (((c >> 3) & 3) * 16 + (l & 15)) * 8 + (c & 7);
                *(ushort4*)&dst[off] = r;
            }
    } else {
        unsigned short* dst = vB + (size_t)b * C_DIM * L_DIM;
#pragma unroll
        for (int ct = 0; ct < 2; ct++)
#pragma unroll
            for (int lt = 0; lt < 4; lt++) {
                const int l = l0 + l_w + lt * 16 + ln15;
                const size_t ibase = ((size_t)(l >> 6) * 32) * 1024 + ((l >> 5) & 1) * 512
                                   + (((l >> 3) & 3) * 16) * 8 + (l & 7);
#pragma unroll
                for (int r = 0; r < 4; r++) {
                    const int vco = (co0 - 128) + co_w + ct * 16 + quad * 4 + r;
                    dst[ibase + (size_t)(vco >> 4) * 1024 + (vco & 15) * 8] = f2h(acc[ct][lt][r]);
                }
            }
    }
}

// ---------------------------------------------------------------------------
// stat_k: per-j softmax stats over an i-chunk of 256, log2 domain.
// Fragment-major q/k read DIRECT from global. Zero LDS, zero barriers.
// Grid (8 ich, 32 jb, 8 b) = 2048 blocks.
// ---------------------------------------------------------------------------
__global__ __launch_bounds__(256) void stat_k(const unsigned short* __restrict__ qT,
                                              const unsigned short* __restrict__ kT,
                                              float* __restrict__ pstat) {
    const int ich = blockIdx.x;
    const int j0  = blockIdx.y * 64;
    const int b   = blockIdx.z;

    const int tid = threadIdx.x;
    const int lane = tid & 63, w = tid >> 6;
    const int ln15 = lane & 15, quad = lane >> 4;
    const int sj = w * 16;
    const int lane8 = lane * 8;

    const unsigned short* qb = qT + (size_t)b * L_DIM * CQ_DIM;
    const unsigned short* kb = kT + (size_t)b * L_DIM * CQ_DIM;

    f16x8 kfr[2];
#pragma unroll
    for (int cc = 0; cc < 2; cc++)
        kfr[cc] = *(const f16x8*)&kb[(size_t)((j0 + sj) >> 4) * 1024 + cc * 512 + lane8];

    float m_run = -1e30f, l_run = 0.f;

    for (int t = 0; t < 4; t++) {
        const int ib = ich * 16 + t * 4;   // i-block base (i0>>4)

        f32x4 sacc[4] = {};
#pragma unroll
        for (int cc = 0; cc < 2; cc++) {
#pragma unroll
            for (int it = 0; it < 4; it++) {
                const f16x8 afr = *(const f16x8*)&qb[(size_t)(ib + it) * 1024 + cc * 512 + lane8];
                sacc[it] = __builtin_amdgcn_mfma_f32_16x16x32_f16(afr, kfr[cc], sacc[it], 0, 0, 0);
            }
        }

        float bm = -1e30f;
#pragma unroll
        for (int it = 0; it < 4; it++)
#pragma unroll
            for (int r = 0; r < 4; r++)
                bm = fmaxf(bm, sacc[it][r]);
        bm = fmaxf(bm, __shfl_xor(bm, 16, 64));
        bm = fmaxf(bm, __shfl_xor(bm, 32, 64));
        const float m_new = fmaxf(m_run, bm);
        const float alpha = exp2f(m_run - m_new);

        float lsum = 0.f;
#pragma unroll
        for (int it = 0; it < 4; it++) {
            float p0 = exp2f(sacc[it][0] - m_new);
            float p1 = exp2f(sacc[it][1] - m_new);
            float p2 = exp2f(sacc[it][2] - m_new);
            float p3 = exp2f(sacc[it][3] - m_new);
            lsum += (p0 + p1) + (p2 + p3);
        }
        lsum += __shfl_xor(lsum, 16, 64);
        lsum += __shfl_xor(lsum, 32, 64);
        l_run = l_run * alpha + lsum;
        m_run = m_new;
    }

    if (quad == 0) {
        const int j = j0 + sj + ln15;
        float* pm = pstat;
        float* pl = pstat + 8 * 8 * 2048;
        pm[((size_t)ich * 8 + b) * 2048 + j] = m_run;
        pl[((size_t)ich * 8 + b) * 2048 + j] = l_run;
    }
}

// ---------------------------------------------------------------------------
// sc_p: P materialization. P[i,j] = exp2(S'[i,j] - m'_j), written ONCE in
// fragment-major B-operand layout (see top). stat_k structure: zero LDS,
// zero barriers, direct fragment reads; per-lane register merge of m'_j.
// Grid (8 ich, 32 jb, 8 b) = 2048 blocks.
// ---------------------------------------------------------------------------
__global__ __launch_bounds__(256) void sc_p(const unsigned short* __restrict__ qT,
                                            const unsigned short* __restrict__ kT,
                                            const float* __restrict__ pstat,
                                            unsigned short* __restrict__ Pm) {
    const int ich = blockIdx.x;
    const int j0  = blockIdx.y * 64;
    const int b   = blockIdx.z;

    const int tid = threadIdx.x;
    const int lane = tid & 63, w = tid >> 6;
    const int ln15 = lane & 15, quad = lane >> 4;
    const int sj = w * 16;
    const int lane8 = lane * 8;

    const unsigned short* qb = qT + (size_t)b * L_DIM * CQ_DIM;
    const unsigned short* kb = kT + (size_t)b * L_DIM * CQ_DIM;
    unsigned short* Pb = Pm + (size_t)b * L_DIM * L_DIM;

    f16x8 kfr[2];
#pragma unroll
    for (int cc = 0; cc < 2; cc++)
        kfr[cc] = *(const f16x8*)&kb[(size_t)((j0 + sj) >> 4) * 1024 + cc * 512 + lane8];

    // per-lane global max for this lane's j (quad-broadcast loads)
    const int jl = j0 + sj + ln15;
    float m = -1e30f;
#pragma unroll
    for (int c = 0; c < 8; c++)
        m = fmaxf(m, pstat[((size_t)c * 8 + b) * 2048 + jl]);

    const int j_tile = (j0 + sj) >> 4;
    const int inchunk = ((quad >> 1) & 1) * 128 + ln15 * 8 + (quad & 1) * 4;

    for (int t = 0; t < 4; t++) {
        const int ib = ich * 16 + t * 4;   // i-block base (i0>>4)

        f32x4 sacc[4] = {};
#pragma unroll
        for (int cc = 0; cc < 2; cc++) {
#pragma unroll
            for (int it = 0; it < 4; it++) {
                const f16x8 afr = *(const f16x8*)&qb[(size_t)(ib + it) * 1024 + cc * 512 + lane8];
                sacc[it] = __builtin_amdgcn_mfma_f32_16x16x32_f16(afr, kfr[cc], sacc[it], 0, 0, 0);
            }
        }

#pragma unroll
        for (int it = 0; it < 4; it++) {
            const int i_t32 = ich * 8 + t * 2 + (it >> 1);
            uint2 u;
            u.x = p2u(exp2f(sacc[it][0] - m), exp2f(sacc[it][1] - m));
            u.y = p2u(exp2f(sacc[it][2] - m), exp2f(sacc[it][3] - m));
            const size_t off = ((size_t)j_tile * 64 + i_t32) * 512
                             + (((it * 2 + (quad >> 1)) & 3) * 128 + ln15 * 8 + (quad & 1) * 4);
            *(uint2*)&Pb[off] = u;
        }
    }
}

// ---------------------------------------------------------------------------
// pv3: pure V x P GEMM (P pre-materialized by sc_p). Block 64j x 128co,
// 4 waves, grid (32, 4, 8). Double-buffered fragment-major LDS via gll16:
// 24 KB/tile -> 48 KB total -> 3 blocks/CU (vs pv2's 2). Per iter: ONE
// barrier, 16 MFMA/wave, zero exp/VALU block, no P-publish. Epilogue scales
// by gamma/l_j (merged in prologue under the stage's flight).
// ---------------------------------------------------------------------------
__global__ __launch_bounds__(256) void pv3(const unsigned short* __restrict__ vB,
                                           const unsigned short* __restrict__ Pm,
                                           const float* __restrict__ pstat,
                                           const float* __restrict__ gamma,
                                           float* __restrict__ out) {
    const int j0  = blockIdx.x * 64;
    const int co0 = blockIdx.y * 128;
    const int b   = blockIdx.z;

    __shared__ __align__(16) unsigned short vbuf[2][8192];   // 2 x 16 KB
    __shared__ __align__(16) unsigned short pbuf[2][4096];   // 2 x 8 KB
    __shared__ float il_s[64];

    const int tid = threadIdx.x;
    const int lane = tid & 63, w = tid >> 6;
    const int ln15 = lane & 15, quad = lane >> 4;
    const int lane8 = lane * 8;

    const unsigned short* vb = vB + (size_t)b * C_DIM * L_DIM;
    const unsigned short* Pb = Pm + (size_t)b * L_DIM * L_DIM;

    // ---- prologue: stage tile 0 (async; overlaps l-merge) ----
    {
        const unsigned short* vsrc = vb + (size_t)(co0 >> 4) * 1024;
#pragma unroll
        for (int s = 0; s < 4; s++)
            gll16(vsrc + (w * 4 + s) * 512 + lane8, &vbuf[0][(w * 4 + s) * 512]);
#pragma unroll
        for (int s = 0; s < 2; s++)
            gll16(Pb + ((size_t)((j0 >> 4) + w) * 64 + s) * 512 + lane8,
                  &pbuf[0][(w * 2 + s) * 512]);
    }

    // ---- merge l_j (log2 domain) under the stage's flight ----
    if (tid < 64) {
        const int j = j0 + tid;
        const float* pm = pstat;
        const float* pl = pstat + 8 * 8 * 2048;
        float m = -1e30f;
        float pmv[8];
#pragma unroll
        for (int c = 0; c < 8; c++) {
            pmv[c] = pm[((size_t)c * 8 + b) * 2048 + j];
            m = fmaxf(m, pmv[c]);
        }
        float l = 0.f;
#pragma unroll
        for (int c = 0; c < 8; c++)
            l = fmaf(pl[((size_t)c * 8 + b) * 2048 + j], exp2f(pmv[c] - m), l);
        il_s[tid] = gamma[0] / l;
    }

    __syncthreads();   // drains vmcnt(0) (stage 0 done) + publishes il_s

    float inv[4];
#pragma unroll
    for (int bb = 0; bb < 4; bb++)
        inv[bb] = il_s[bb * 16 + ln15];

    f32x4 oacc[2][4] = {};   // [co-tile][j-tile]
    int cur = 0;

    for (int i0 = 0; i0 < L_DIM; i0 += 64) {
        // ---- issue next-tile stage (in flight until end-of-iter barrier) ----
        const int i1 = i0 + 64;
        if (i1 < L_DIM) {
            const unsigned short* vsrc = vb + ((size_t)(i1 >> 6) * 32 + (co0 >> 4)) * 1024;
            const int nxt = cur ^ 1;
#pragma unroll
            for (int s = 0; s < 4; s++)
                gll16(vsrc + (w * 4 + s) * 512 + lane8, &vbuf[nxt][(w * 4 + s) * 512]);
#pragma unroll
            for (int s = 0; s < 2; s++)
                gll16(Pb + ((size_t)((j0 >> 4) + w) * 64 + (i1 >> 5) + s) * 512 + lane8,
                      &pbuf[nxt][(w * 2 + s) * 512]);
        }

        // ---- GEMM: oacc += V[32co x 64i] * P[64i x 64j] ----
        __builtin_amdgcn_s_setprio(1);
#pragma unroll
        for (int cc = 0; cc < 2; cc++) {
            f16x8 afr[2], bfr[4];
#pragma unroll
            for (int t = 0; t < 2; t++)
                afr[t] = *(const f16x8*)&vbuf[cur][((w * 2 + t) * 2 + cc) * 512 + lane8];
#pragma unroll
            for (int t = 0; t < 4; t++)
                bfr[t] = *(const f16x8*)&pbuf[cur][(t * 2 + cc) * 512 + lane8];
#pragma unroll
            for (int a = 0; a < 2; a++)
#pragma unroll
                for (int bb = 0; bb < 4; bb++)
                    oacc[a][bb] = __builtin_amdgcn_mfma_f32_16x16x32_f16(afr[a], bfr[bb], oacc[a][bb], 0, 0, 0);
        }
        __builtin_amdgcn_s_setprio(0);

        __syncthreads();   // implicit vmcnt(0): next-tile stage complete; all reads done
        cur ^= 1;
    }

    // ---- epilogue: out = oacc * (gamma / l_j) ----
    const int wco = w * 32;
#pragma unroll
    for (int a = 0; a < 2; a++)
#pragma unroll
        for (int r = 0; r < 4; r++) {
            const int co = co0 + wco + a * 16 + quad * 4 + r;
            float* ob = out + ((size_t)b * C_DIM + co) * L_DIM + j0;
#pragma unroll
            for (int bb = 0; bb < 4; bb++)
                ob[bb * 16 + ln15] = oacc[a][bb][r] * inv[bb];
        }
}

// ---------------------------------------------------------------------------
// pv2: round-11 proven fused path (fallback when workspace lacks room for P).
// ---------------------------------------------------------------------------
__global__ __launch_bounds__(256) void pv2(const unsigned short* __restrict__ qT,
                                           const unsigned short* __restrict__ kT,
                                           const unsigned short* __restrict__ vB,
                                           const float* __restrict__ pstat,
                                           const float* __restrict__ gamma,
                                           float* __restrict__ out) {
    const int j0  = blockIdx.x * 64;
    const int co0 = blockIdx.y * 128;
    const int b   = blockIdx.z;

    __shared__ __align__(16) unsigned short qbuf[2][4096];
    __shared__ __align__(16) unsigned short vbuf[2][8192];
    __shared__ unsigned short pps[64 * 68];
    __shared__ float mj_s[64];
    __shared__ float il_s[64];

    const int tid = threadIdx.x;
    const int lane = tid & 63, w = tid >> 6;
    const int ln15 = lane & 15, quad = lane >> 4;
    const int lane8 = lane * 8;

    const unsigned short* qb = qT + (size_t)b * L_DIM * CQ_DIM;
    const unsigned short* kb = kT + (size_t)b * L_DIM * CQ_DIM;
    const unsigned short* vb = vB + (size_t)b * C_DIM * L_DIM;

    const int sj  = w * 16;
    const int wco = w * 32;

    {
        const unsigned short* vsrc = vb + (size_t)(co0 >> 4) * 1024;
#pragma unroll
        for (int s = 0; s < 2; s++)
            gll16(qb + (w * 2 + s) * 512 + lane8, &qbuf[0][(w * 2 + s) * 512]);
#pragma unroll
        for (int s = 0; s < 4; s++)
            gll16(vsrc + (w * 4 + s) * 512 + lane8, &vbuf[0][(w * 4 + s) * 512]);
    }

    if (tid < 64) {
        const int j = j0 + tid;
        const float* pm = pstat;
        const float* pl = pstat + 8 * 8 * 2048;
        float m = -1e30f;
        float pmv[8];
#pragma unroll
        for (int c = 0; c < 8; c++) {
            pmv[c] = pm[((size_t)c * 8 + b) * 2048 + j];
            m = fmaxf(m, pmv[c]);
        }
        float l = 0.f;
#pragma unroll
        for (int c = 0; c < 8; c++)
            l = fmaf(pl[((size_t)c * 8 + b) * 2048 + j], exp2f(pmv[c] - m), l);
        mj_s[tid] = m;
        il_s[tid] = gamma[0] / l;
    }

    f16x8 kfr[2];
#pragma unroll
    for (int cc = 0; cc < 2; cc++)
        kfr[cc] = *(const f16x8*)&kb[(size_t)((j0 + sj) >> 4) * 1024 + cc * 512 + lane8];

    __syncthreads();

    const float m_lane = mj_s[sj + ln15];
    float inv[4];
#pragma unroll
    for (int bb = 0; bb < 4; bb++)
        inv[bb] = il_s[bb * 16 + ln15];

    f32x4 oacc[2][4] = {};
    int cur = 0;

    for (int i0 = 0; i0 < L_DIM; i0 += 64) {
        const int i1 = i0 + 64;
        if (i1 < L_DIM) {
            const unsigned short* qsrc = qb + (size_t)(i1 >> 4) * 1024;
            const unsigned short* vsrc = vb + ((size_t)(i1 >> 6) * 32 + (co0 >> 4)) * 1024;
            const int nxt = cur ^ 1;
#pragma unroll
            for (int s = 0; s < 2; s++)
                gll16(qsrc + (w * 2 + s) * 512 + lane8, &qbuf[nxt][(w * 2 + s) * 512]);
#pragma unroll
            for (int s = 0; s < 4; s++)
                gll16(vsrc + (w * 4 + s) * 512 + lane8, &vbuf[nxt][(w * 4 + s) * 512]);
        }

        f32x4 sacc[4] = {};
        __builtin_amdgcn_s_setprio(1);
#pragma unroll
        for (int cc = 0; cc < 2; cc++) {
#pragma unroll
            for (int it = 0; it < 4; it++) {
                const f16x8 afr = *(const f16x8*)&qbuf[cur][(it * 2 + cc) * 512 + lane8];
                sacc[it] = __builtin_amdgcn_mfma_f32_16x16x32_f16(afr, kfr[cc], sacc[it], 0, 0, 0);
            }
        }
        __builtin_amdgcn_s_setprio(0);

        const int j = sj + ln15;
#pragma unroll
        for (int it = 0; it < 4; it++) {
            float p0 = exp2f(sacc[it][0] - m_lane);
            float p1 = exp2f(sacc[it][1] - m_lane);
            float p2 = exp2f(sacc[it][2] - m_lane);
            float p3 = exp2f(sacc[it][3] - m_lane);
            uint2 u;
            u.x = p2u(p0, p1);
            u.y = p2u(p2, p3);
            *(uint2*)&pps[j * 68 + it * 16 + quad * 4] = u;
        }

        asm volatile("s_waitcnt lgkmcnt(0)" ::: "memory");
        __builtin_amdgcn_s_barrier();
        __builtin_amdgcn_sched_barrier(0);

        __builtin_amdgcn_s_setprio(1);
#pragma unroll
        for (int cc = 0; cc < 2; cc++) {
            f16x8 afr[2], bfr[4];
#pragma unroll
            for (int t = 0; t < 2; t++)
                afr[t] = *(const f16x8*)&vbuf[cur][((w * 2 + t) * 2 + cc) * 512 + lane8];
#pragma unroll
            for (int t = 0; t < 4; t++)
                bfr[t] = *(const f16x8*)&pps[(t * 16 + ln15) * 68 + cc * 32 + quad * 8];
#pragma unroll
            for (int a = 0; a < 2; a++)
#pragma unroll
                for (int bb = 0; bb < 4; bb++)
                    oacc[a][bb] = __builtin_amdgcn_mfma_f32_16x16x32_f16(afr[a], bfr[bb], oacc[a][bb], 0, 0, 0);
        }
        __builtin_amdgcn_s_setprio(0);

        __syncthreads();
        cur ^= 1;
    }

#pragma unroll
    for (int a = 0; a < 2; a++)
#pragma unroll
        for (int r = 0; r < 4; r++) {
            const int co = co0 + wco + a * 16 + quad * 4 + r;
            float* ob = out + ((size_t)b * C_DIM + co) * L_DIM + j0;
#pragma unroll
            for (int bb = 0; bb < 4; bb++)
                ob[bb * 16 + ln15] = oacc[a][bb][r] * inv[bb];
        }
}

// ---------------------------------------------------------------------------
extern "C" void kernel_launch(void* const* d_in, const int* in_sizes, int n_in,
                              void* d_out, int out_size, void* d_ws, size_t ws_size,
                              hipStream_t stream) {
    const float* x     = (const float*)d_in[0];
    const float* Wq    = (const float*)d_in[1];
    const float* Wk    = (const float*)d_in[2];
    const float* Wv    = (const float*)d_in[3];
    const float* gamma = (const float*)d_in[4];
    float* out = (float*)d_out;

    unsigned short* ws_h = (unsigned short*)d_ws;
    unsigned short* qT = ws_h;                        // 8*2048*64   = 1,048,576
    unsigned short* kT = qT + 1048576;
    unsigned short* vB = kT + 1048576;                // 8*512*2048  = 8,388,608
    unsigned short* xT = vB + 8388608;                // 8*2048*512  = 8,388,608
    unsigned short* Wh = xT + 8388608;                // 3*640*512   = 983,040
    unsigned short* Pm = Wh + 983040;                 // 8*2048*2048 = 33,554,432
    // stats reuse the xT region (dead after conv_all): 2 * 8*8*2048 floats = 1 MB
    float* pstat = (float*)xT;

    const size_t need_bytes = ((size_t)19857408 + 33554432) * 2;  // ~107 MB

    prep_w  <<<3840, 256, 0, stream>>>(Wq, Wk, Wv, Wh);
    prep_x  <<<dim3(32, 8, 8), 256, 0, stream>>>(x, xT);
    conv_all<<<dim3(16, 10, 8), 256, 0, stream>>>(Wh, xT, qT, kT, vB);
    stat_k  <<<dim3(8, 32, 8), 256, 0, stream>>>(qT, kT, pstat);
    if (ws_size >= need_bytes) {
        sc_p <<<dim3(8, 32, 8), 256, 0, stream>>>(qT, kT, pstat, Pm);
        pv3  <<<dim3(32, 4, 8), 256, 0, stream>>>(vB, Pm, pstat, gamma, out);
    } else {
        pv2  <<<dim3(32, 4, 8), 256, 0, stream>>>(qT, kT, vB, pstat, gamma, out);
    }
}

// Round 13
// 217.785 us; speedup vs baseline: 1.3092x; 1.0571x over previous
//
#include <hip/hip_runtime.h>
#include <cstddef>
#include <math.h>

#define L_DIM 2048
#define C_DIM 512
#define CQ_DIM 64
#define B_DIM 8
#define LOG2E 1.44269504088896340736f

typedef _Float16 f16x8 __attribute__((ext_vector_type(8)));
typedef __fp16 fp16x2_t __attribute__((ext_vector_type(2)));
typedef float f32x4 __attribute__((ext_vector_type(4)));

typedef __attribute__((address_space(3))) unsigned int u32_lds;
typedef __attribute__((address_space(1))) const unsigned int u32_glob;

__device__ __forceinline__ unsigned short f2h(float f) {
    union { _Float16 h; unsigned short u; } v;
    v.h = (_Float16)f;
    return v.u;
}

// packed fp32x2 -> fp16x2 (RTZ) as uint
__device__ __forceinline__ unsigned p2u(float a, float b) {
    union { fp16x2_t h; unsigned u; } v;
    v.h = __builtin_amdgcn_cvt_pkrtz(a, b);
    return v.u;
}

// async global->LDS, 16B per lane: LDS dest = wave-uniform base + lane*16
__device__ __forceinline__ void gll16(const unsigned short* g, unsigned short* l) {
    __builtin_amdgcn_global_load_lds((u32_glob*)(const void*)g,
                                     (u32_lds*)(void*)l, 16, 0, 0);
}

// ---------------------------------------------------------------------------
// Fragment-major layouts (producer-controlled):
//  qF/kF per b: elem off = (i>>4)*1024 + (c>>5)*512 + ((c>>3)&3)*128 + (i&15)*8 + (c&7)
//  vF per b:    elem off = ((i>>6)*32 + (co>>4))*1024 + ((i>>5)&1)*512
//                          + ((i>>3)&3)*128 + (co&15)*8 + (i&7)
//  P  per b:    elem off = ((j>>4)*64 + (i>>5))*512 + ((i>>3)&3)*128 + (j&15)*8 + (i&7)
//  A wave's f16x8 MFMA fragment = 16B at (chunk base + lane*16): linear,
//  conflict-free, global_load_lds-verbatim, fully coalesced.
// ---------------------------------------------------------------------------

// ---------------------------------------------------------------------------
// prep_w: Wq/Wk/Wv (fp32 [co][ci][3]) -> Wh fp16 [t][640co][512ci]
// ---------------------------------------------------------------------------
__global__ __launch_bounds__(256) void prep_w(const float* __restrict__ Wq,
                                              const float* __restrict__ Wk,
                                              const float* __restrict__ Wv,
                                              unsigned short* __restrict__ Wh) {
    const int idx = blockIdx.x * 256 + threadIdx.x;
    const int ci = idx & 511;
    const int co = (idx >> 9) % 640;
    const int t  = idx / (640 * 512);
    float w;
    if (co < 64)       w = Wq[(size_t)co * 1536 + ci * 3 + t];
    else if (co < 128) w = Wk[(size_t)(co - 64) * 1536 + ci * 3 + t];
    else               w = Wv[(size_t)(co - 128) * 1536 + ci * 3 + t];
    Wh[idx] = f2h(w);
}

// ---------------------------------------------------------------------------
// prep_x: x fp32 [b][ci][l] -> xT fp16 [b][l][512ci]. 64ci x 64l tile per block.
// ---------------------------------------------------------------------------
__global__ __launch_bounds__(256) void prep_x(const float* __restrict__ x,
                                              unsigned short* __restrict__ xT) {
    const int l0  = blockIdx.x * 64;
    const int ci0 = blockIdx.y * 64;
    const int b   = blockIdx.z;

    __shared__ float xs[64][68];
    const int tid = threadIdx.x;
    const float* xb = x + ((size_t)b * C_DIM + ci0) * L_DIM;

    for (int idx = tid; idx < 64 * 16; idx += 256) {
        int ci = idx >> 4, lq = idx & 15;
        *(float4*)&xs[ci][lq * 4] = *(const float4*)&xb[(size_t)ci * L_DIM + l0 + lq * 4];
    }
    __syncthreads();

    unsigned short* ob = xT + ((size_t)b * L_DIM + l0) * C_DIM + ci0;
    for (int idx = tid; idx < 64 * 8; idx += 256) {
        int l = idx >> 3, c8 = idx & 7;
        ushort4 r0, r1;
        r0.x = f2h(xs[c8 * 8 + 0][l]); r0.y = f2h(xs[c8 * 8 + 1][l]);
        r0.z = f2h(xs[c8 * 8 + 2][l]); r0.w = f2h(xs[c8 * 8 + 3][l]);
        r1.x = f2h(xs[c8 * 8 + 4][l]); r1.y = f2h(xs[c8 * 8 + 5][l]);
        r1.z = f2h(xs[c8 * 8 + 6][l]); r1.w = f2h(xs[c8 * 8 + 7][l]);
        *(ushort4*)&ob[(size_t)l * C_DIM + c8 * 8] = r0;
        *(ushort4*)&ob[(size_t)l * C_DIM + c8 * 8 + 4] = r1;
    }
}

// ---------------------------------------------------------------------------
// conv_all: out[co,l] = sum_t sum_ci Wh[t][co][ci] * x[ci][l+t-1] via MFMA.
// Round-8 proven version: BK=32, reg-staged LDS tiles (26 KB -> high occ).
// q output (co0==0) pre-scaled by log2(e). Epilogue: fragment-major q/k/v.
// ---------------------------------------------------------------------------
__global__ __launch_bounds__(256) void conv_all(const unsigned short* __restrict__ Wh,
                                                const unsigned short* __restrict__ xT,
                                                unsigned short* __restrict__ qT,
                                                unsigned short* __restrict__ kT,
                                                unsigned short* __restrict__ vB) {
    const int l0  = blockIdx.x * 128;
    const int co0 = blockIdx.y * 64;
    const int b   = blockIdx.z;

    __shared__ unsigned short As[3][64][40];
    __shared__ unsigned short Bs[130][40];

    const int tid  = threadIdx.x;
    const int lane = tid & 63, w = tid >> 6;
    const int ln15 = lane & 15, quad = lane >> 4;

    const int co_w = (w & 1) * 32;
    const int l_w  = (w >> 1) * 64;

    const unsigned short* xb = xT + (size_t)b * L_DIM * C_DIM;

    f32x4 acc[2][4] = {};

    for (int ci0 = 0; ci0 < C_DIM; ci0 += 32) {
        __syncthreads();
        for (int idx = tid; idx < 768; idx += 256) {
            int t = idx >> 8, co = (idx >> 2) & 63, c8 = idx & 3;
            *(float4*)&As[t][co][c8 * 8] =
                *(const float4*)&Wh[(((size_t)t * 640) + co0 + co) * C_DIM + ci0 + c8 * 8];
        }
        for (int idx = tid; idx < 520; idx += 256) {
            int la = idx >> 2, c8 = idx & 3;
            int l = l0 - 1 + la;
            float4 vx = {0.f, 0.f, 0.f, 0.f};
            if (l >= 0 && l < L_DIM)
                vx = *(const float4*)&xb[(size_t)l * C_DIM + ci0 + c8 * 8];
            *(float4*)&Bs[la][c8 * 8] = vx;
        }
        __syncthreads();

#pragma unroll
        for (int t = 0; t < 3; t++) {
            f16x8 a[2], bfr[4];
#pragma unroll
            for (int ct = 0; ct < 2; ct++)
                a[ct] = *(const f16x8*)&As[t][co_w + ct * 16 + ln15][quad * 8];
#pragma unroll
            for (int lt = 0; lt < 4; lt++)
                bfr[lt] = *(const f16x8*)&Bs[l_w + lt * 16 + ln15 + t][quad * 8];
#pragma unroll
            for (int ct = 0; ct < 2; ct++)
#pragma unroll
                for (int lt = 0; lt < 4; lt++)
                    acc[ct][lt] = __builtin_amdgcn_mfma_f32_16x16x32_f16(a[ct], bfr[lt], acc[ct][lt], 0, 0, 0);
        }
    }

    if (co0 < 128) {
        const float qs = (co0 == 0) ? LOG2E : 1.0f;   // fold log2(e) into q
        unsigned short* dst = (co0 == 0 ? qT : kT) + (size_t)b * L_DIM * CQ_DIM;
#pragma unroll
        for (int ct = 0; ct < 2; ct++)
#pragma unroll
            for (int lt = 0; lt < 4; lt++) {
                const int l = l0 + l_w + lt * 16 + ln15;
                const int c = co_w + ct * 16 + quad * 4;   // 4 consecutive c, same 8-chunk
                ushort4 r;
                r.x = f2h(acc[ct][lt][0] * qs); r.y = f2h(acc[ct][lt][1] * qs);
                r.z = f2h(acc[ct][lt][2] * qs); r.w = f2h(acc[ct][lt][3] * qs);
                const size_t off = (size_t)(l >> 4) * 1024 + (c >> 5) * 512
                                 + (((c >> 3) & 3) * 16 + (l & 15)) * 8 + (c & 7);
                *(ushort4*)&dst[off] = r;
            }
    } else {
        unsigned short* dst = vB + (size_t)b * C_DIM * L_DIM;
#pragma unroll
        for (int ct = 0; ct < 2; ct++)
#pragma unroll
            for (int lt = 0; lt < 4; lt++) {
                const int l = l0 + l_w + lt * 16 + ln15;
                const size_t ibase = ((size_t)(l >> 6) * 32) * 1024 + ((l >> 5) & 1) * 512
                                   + (((l >> 3) & 3) * 16) * 8 + (l & 7);
#pragma unroll
                for (int r = 0; r < 4; r++) {
                    const int vco = (co0 - 128) + co_w + ct * 16 + quad * 4 + r;
                    dst[ibase + (size_t)(vco >> 4) * 1024 + (vco & 15) * 8] = f2h(acc[ct][lt][r]);
                }
            }
    }
}

// ---------------------------------------------------------------------------
// stat_k: per-j softmax stats over an i-chunk of 256, log2 domain.
// Fragment-major q/k read DIRECT from global. Zero LDS, zero barriers.
// Grid (8 ich, 32 jb, 8 b) = 2048 blocks.
// ---------------------------------------------------------------------------
__global__ __launch_bounds__(256) void stat_k(const unsigned short* __restrict__ qT,
                                              const unsigned short* __restrict__ kT,
                                              float* __restrict__ pstat) {
    const int ich = blockIdx.x;
    const int j0  = blockIdx.y * 64;
    const int b   = blockIdx.z;

    const int tid = threadIdx.x;
    const int lane = tid & 63, w = tid >> 6;
    const int ln15 = lane & 15, quad = lane >> 4;
    const int sj = w * 16;
    const int lane8 = lane * 8;

    const unsigned short* qb = qT + (size_t)b * L_DIM * CQ_DIM;
    const unsigned short* kb = kT + (size_t)b * L_DIM * CQ_DIM;

    f16x8 kfr[2];
#pragma unroll
    for (int cc = 0; cc < 2; cc++)
        kfr[cc] = *(const f16x8*)&kb[(size_t)((j0 + sj) >> 4) * 1024 + cc * 512 + lane8];

    float m_run = -1e30f, l_run = 0.f;

    for (int t = 0; t < 4; t++) {
        const int ib = ich * 16 + t * 4;   // i-block base (i0>>4)

        f32x4 sacc[4] = {};
#pragma unroll
        for (int cc = 0; cc < 2; cc++) {
#pragma unroll
            for (int it = 0; it < 4; it++) {
                const f16x8 afr = *(const f16x8*)&qb[(size_t)(ib + it) * 1024 + cc * 512 + lane8];
                sacc[it] = __builtin_amdgcn_mfma_f32_16x16x32_f16(afr, kfr[cc], sacc[it], 0, 0, 0);
            }
        }

        float bm = -1e30f;
#pragma unroll
        for (int it = 0; it < 4; it++)
#pragma unroll
            for (int r = 0; r < 4; r++)
                bm = fmaxf(bm, sacc[it][r]);
        bm = fmaxf(bm, __shfl_xor(bm, 16, 64));
        bm = fmaxf(bm, __shfl_xor(bm, 32, 64));
        const float m_new = fmaxf(m_run, bm);
        const float alpha = exp2f(m_run - m_new);

        float lsum = 0.f;
#pragma unroll
        for (int it = 0; it < 4; it++) {
            float p0 = exp2f(sacc[it][0] - m_new);
            float p1 = exp2f(sacc[it][1] - m_new);
            float p2 = exp2f(sacc[it][2] - m_new);
            float p3 = exp2f(sacc[it][3] - m_new);
            lsum += (p0 + p1) + (p2 + p3);
        }
        lsum += __shfl_xor(lsum, 16, 64);
        lsum += __shfl_xor(lsum, 32, 64);
        l_run = l_run * alpha + lsum;
        m_run = m_new;
    }

    if (quad == 0) {
        const int j = j0 + sj + ln15;
        float* pm = pstat;
        float* pl = pstat + 8 * 8 * 2048;
        pm[((size_t)ich * 8 + b) * 2048 + j] = m_run;
        pl[((size_t)ich * 8 + b) * 2048 + j] = l_run;
    }
}

// ---------------------------------------------------------------------------
// sc_p: P materialization. P[i,j] = exp2(S'[i,j] - m'_j), written ONCE in
// fragment-major B-operand layout. stat_k structure: zero LDS, zero barriers.
// Grid (8 ich, 32 jb, 8 b) = 2048 blocks.
// ---------------------------------------------------------------------------
__global__ __launch_bounds__(256) void sc_p(const unsigned short* __restrict__ qT,
                                            const unsigned short* __restrict__ kT,
                                            const float* __restrict__ pstat,
                                            unsigned short* __restrict__ Pm) {
    const int ich = blockIdx.x;
    const int j0  = blockIdx.y * 64;
    const int b   = blockIdx.z;

    const int tid = threadIdx.x;
    const int lane = tid & 63, w = tid >> 6;
    const int ln15 = lane & 15, quad = lane >> 4;
    const int sj = w * 16;
    const int lane8 = lane * 8;

    const unsigned short* qb = qT + (size_t)b * L_DIM * CQ_DIM;
    const unsigned short* kb = kT + (size_t)b * L_DIM * CQ_DIM;
    unsigned short* Pb = Pm + (size_t)b * L_DIM * L_DIM;

    f16x8 kfr[2];
#pragma unroll
    for (int cc = 0; cc < 2; cc++)
        kfr[cc] = *(const f16x8*)&kb[(size_t)((j0 + sj) >> 4) * 1024 + cc * 512 + lane8];

    // per-lane global max for this lane's j (quad-broadcast loads)
    const int jl = j0 + sj + ln15;
    float m = -1e30f;
#pragma unroll
    for (int c = 0; c < 8; c++)
        m = fmaxf(m, pstat[((size_t)c * 8 + b) * 2048 + jl]);

    const int j_tile = (j0 + sj) >> 4;

    for (int t = 0; t < 4; t++) {
        const int ib = ich * 16 + t * 4;   // i-block base (i0>>4)

        f32x4 sacc[4] = {};
#pragma unroll
        for (int cc = 0; cc < 2; cc++) {
#pragma unroll
            for (int it = 0; it < 4; it++) {
                const f16x8 afr = *(const f16x8*)&qb[(size_t)(ib + it) * 1024 + cc * 512 + lane8];
                sacc[it] = __builtin_amdgcn_mfma_f32_16x16x32_f16(afr, kfr[cc], sacc[it], 0, 0, 0);
            }
        }

#pragma unroll
        for (int it = 0; it < 4; it++) {
            const int i_t32 = ich * 8 + t * 2 + (it >> 1);
            uint2 u;
            u.x = p2u(exp2f(sacc[it][0] - m), exp2f(sacc[it][1] - m));
            u.y = p2u(exp2f(sacc[it][2] - m), exp2f(sacc[it][3] - m));
            const size_t off = ((size_t)j_tile * 64 + i_t32) * 512
                             + (((it * 2 + (quad >> 1)) & 3) * 128 + ln15 * 8 + (quad & 1) * 4);
            *(uint2*)&Pb[off] = u;
        }
    }
}

// ---------------------------------------------------------------------------
// pv3: pure V x P GEMM (P pre-materialized by sc_p). 512-THREAD BLOCKS:
// tile 128j x 128co, 8 waves = 4 co-groups x 2 j-halves; wave (cw, jh) owns
// O[32co x 64j] (same per-wave profile as r12 pv3: oacc 32 VGPR, 16 MFMA/iter,
// 12 ds_read_b128, 4 gll16). Grid (16, 4, 8) = 512 blocks = exactly 2/CU;
// LDS 64 KB (vbuf 2x16 + pbuf 2x16) -> 2 blocks/CU -> 16 waves/CU (50% cap,
// was 12/37.5%). V HBM traffic halves (16 j-blocks re-read V, was 32).
// Same 2-phase dbuf schedule: stage issued at iter top, drained at the
// single end-of-iter __syncthreads.
// ---------------------------------------------------------------------------
__global__ __launch_bounds__(512) void pv3(const unsigned short* __restrict__ vB,
                                           const unsigned short* __restrict__ Pm,
                                           const float* __restrict__ pstat,
                                           const float* __restrict__ gamma,
                                           float* __restrict__ out) {
    const int j0  = blockIdx.x * 128;
    const int co0 = blockIdx.y * 128;
    const int b   = blockIdx.z;

    __shared__ __align__(16) unsigned short vbuf[2][8192];   // 2 x 16 KB
    __shared__ __align__(16) unsigned short pbuf[2][8192];   // 2 x 16 KB
    __shared__ float il_s[128];

    const int tid = threadIdx.x;
    const int lane = tid & 63, w = tid >> 6;
    const int ln15 = lane & 15, quad = lane >> 4;
    const int lane8 = lane * 8;

    const int cw = w & 3;    // co 32-group
    const int jh = w >> 2;   // j 64-half

    const unsigned short* vb = vB + (size_t)b * C_DIM * L_DIM;
    const unsigned short* Pb = Pm + (size_t)b * L_DIM * L_DIM;

    // stage tile at i0 into buffer bi: 16 V chunks + 16 P chunks, 4/wave
#define PV3_STAGE(i0_, bi_)                                                        \
    _Pragma("unroll")                                                              \
    for (int s = 0; s < 4; s++) {                                                  \
        const int c = w * 4 + s;                                                   \
        if (c < 16) {                                                              \
            const int ct = c >> 1, ic = c & 1;                                     \
            gll16(vb + (((size_t)((i0_) >> 6) * 32 + (co0 >> 4) + ct) * 1024       \
                        + ic * 512) + lane8,                                       \
                  &vbuf[bi_][c * 512]);                                            \
        } else {                                                                   \
            const int pc = c - 16, jt = pc >> 1, ic = pc & 1;                      \
            gll16(Pb + ((size_t)((j0 >> 4) + jt) * 64 + ((i0_) >> 5) + ic) * 512   \
                     + lane8,                                                      \
                  &pbuf[bi_][pc * 512]);                                           \
        }                                                                          \
    }

    // ---- prologue: stage tile 0 (async; overlaps l-merge) ----
    PV3_STAGE(0, 0);

    // ---- merge l_j (log2 domain) under the stage's flight ----
    if (tid < 128) {
        const int j = j0 + tid;
        const float* pm = pstat;
        const float* pl = pstat + 8 * 8 * 2048;
        float m = -1e30f;
        float pmv[8];
#pragma unroll
        for (int c = 0; c < 8; c++) {
            pmv[c] = pm[((size_t)c * 8 + b) * 2048 + j];
            m = fmaxf(m, pmv[c]);
        }
        float l = 0.f;
#pragma unroll
        for (int c = 0; c < 8; c++)
            l = fmaf(pl[((size_t)c * 8 + b) * 2048 + j], exp2f(pmv[c] - m), l);
        il_s[tid] = gamma[0] / l;
    }

    __syncthreads();   // drains vmcnt(0) (stage 0 done) + publishes il_s

    float inv[4];
#pragma unroll
    for (int bb = 0; bb < 4; bb++)
        inv[bb] = il_s[jh * 64 + bb * 16 + ln15];

    f32x4 oacc[2][4] = {};   // [co-tile][j-tile] for this wave's 32co x 64j
    int cur = 0;

    for (int i0 = 0; i0 < L_DIM; i0 += 64) {
        // ---- issue next-tile stage (in flight until end-of-iter barrier) ----
        const int i1 = i0 + 64;
        if (i1 < L_DIM) {
            const int nxt = cur ^ 1;
            PV3_STAGE(i1, nxt);
        }

        // ---- GEMM: oacc += V[32co x 64i] * P[64i x 64j] ----
        __builtin_amdgcn_s_setprio(1);
#pragma unroll
        for (int cc = 0; cc < 2; cc++) {
            f16x8 afr[2], bfr[4];
#pragma unroll
            for (int t = 0; t < 2; t++)
                afr[t] = *(const f16x8*)&vbuf[cur][((cw * 2 + t) * 2 + cc) * 512 + lane8];
#pragma unroll
            for (int t = 0; t < 4; t++)
                bfr[t] = *(const f16x8*)&pbuf[cur][((jh * 4 + t) * 2 + cc) * 512 + lane8];
#pragma unroll
            for (int a = 0; a < 2; a++)
#pragma unroll
                for (int bb = 0; bb < 4; bb++)
                    oacc[a][bb] = __builtin_amdgcn_mfma_f32_16x16x32_f16(afr[a], bfr[bb], oacc[a][bb], 0, 0, 0);
        }
        __builtin_amdgcn_s_setprio(0);

        __syncthreads();   // implicit vmcnt(0): next-tile stage complete; all reads done
        cur ^= 1;
    }

    // ---- epilogue: out = oacc * (gamma / l_j) ----
#pragma unroll
    for (int a = 0; a < 2; a++)
#pragma unroll
        for (int r = 0; r < 4; r++) {
            const int co = co0 + cw * 32 + a * 16 + quad * 4 + r;
            float* ob = out + ((size_t)b * C_DIM + co) * L_DIM + j0 + jh * 64;
#pragma unroll
            for (int bb = 0; bb < 4; bb++)
                ob[bb * 16 + ln15] = oacc[a][bb][r] * inv[bb];
        }
#undef PV3_STAGE
}

// ---------------------------------------------------------------------------
// pv2: round-11 proven fused path (fallback when workspace lacks room for P).
// ---------------------------------------------------------------------------
__global__ __launch_bounds__(256) void pv2(const unsigned short* __restrict__ qT,
                                           const unsigned short* __restrict__ kT,
                                           const unsigned short* __restrict__ vB,
                                           const float* __restrict__ pstat,
                                           const float* __restrict__ gamma,
                                           float* __restrict__ out) {
    const int j0  = blockIdx.x * 64;
    const int co0 = blockIdx.y * 128;
    const int b   = blockIdx.z;

    __shared__ __align__(16) unsigned short qbuf[2][4096];
    __shared__ __align__(16) unsigned short vbuf[2][8192];
    __shared__ unsigned short pps[64 * 68];
    __shared__ float mj_s[64];
    __shared__ float il_s[64];

    const int tid = threadIdx.x;
    const int lane = tid & 63, w = tid >> 6;
    const int ln15 = lane & 15, quad = lane >> 4;
    const int lane8 = lane * 8;

    const unsigned short* qb = qT + (size_t)b * L_DIM * CQ_DIM;
    const unsigned short* kb = kT + (size_t)b * L_DIM * CQ_DIM;
    const unsigned short* vb = vB + (size_t)b * C_DIM * L_DIM;

    const int sj  = w * 16;
    const int wco = w * 32;

    {
        const unsigned short* vsrc = vb + (size_t)(co0 >> 4) * 1024;
#pragma unroll
        for (int s = 0; s < 2; s++)
            gll16(qb + (w * 2 + s) * 512 + lane8, &qbuf[0][(w * 2 + s) * 512]);
#pragma unroll
        for (int s = 0; s < 4; s++)
            gll16(vsrc + (w * 4 + s) * 512 + lane8, &vbuf[0][(w * 4 + s) * 512]);
    }

    if (tid < 64) {
        const int j = j0 + tid;
        const float* pm = pstat;
        const float* pl = pstat + 8 * 8 * 2048;
        float m = -1e30f;
        float pmv[8];
#pragma unroll
        for (int c = 0; c < 8; c++) {
            pmv[c] = pm[((size_t)c * 8 + b) * 2048 + j];
            m = fmaxf(m, pmv[c]);
        }
        float l = 0.f;
#pragma unroll
        for (int c = 0; c < 8; c++)
            l = fmaf(pl[((size_t)c * 8 + b) * 2048 + j], exp2f(pmv[c] - m), l);
        mj_s[tid] = m;
        il_s[tid] = gamma[0] / l;
    }

    f16x8 kfr[2];
#pragma unroll
    for (int cc = 0; cc < 2; cc++)
        kfr[cc] = *(const f16x8*)&kb[(size_t)((j0 + sj) >> 4) * 1024 + cc * 512 + lane8];

    __syncthreads();

    const float m_lane = mj_s[sj + ln15];
    float inv[4];
#pragma unroll
    for (int bb = 0; bb < 4; bb++)
        inv[bb] = il_s[bb * 16 + ln15];

    f32x4 oacc[2][4] = {};
    int cur = 0;

    for (int i0 = 0; i0 < L_DIM; i0 += 64) {
        const int i1 = i0 + 64;
        if (i1 < L_DIM) {
            const unsigned short* qsrc = qb + (size_t)(i1 >> 4) * 1024;
            const unsigned short* vsrc = vb + ((size_t)(i1 >> 6) * 32 + (co0 >> 4)) * 1024;
            const int nxt = cur ^ 1;
#pragma unroll
            for (int s = 0; s < 2; s++)
                gll16(qsrc + (w * 2 + s) * 512 + lane8, &qbuf[nxt][(w * 2 + s) * 512]);
#pragma unroll
            for (int s = 0; s < 4; s++)
                gll16(vsrc + (w * 4 + s) * 512 + lane8, &vbuf[nxt][(w * 4 + s) * 512]);
        }

        f32x4 sacc[4] = {};
        __builtin_amdgcn_s_setprio(1);
#pragma unroll
        for (int cc = 0; cc < 2; cc++) {
#pragma unroll
            for (int it = 0; it < 4; it++) {
                const f16x8 afr = *(const f16x8*)&qbuf[cur][(it * 2 + cc) * 512 + lane8];
                sacc[it] = __builtin_amdgcn_mfma_f32_16x16x32_f16(afr, kfr[cc], sacc[it], 0, 0, 0);
            }
        }
        __builtin_amdgcn_s_setprio(0);

        const int j = sj + ln15;
#pragma unroll
        for (int it = 0; it < 4; it++) {
            float p0 = exp2f(sacc[it][0] - m_lane);
            float p1 = exp2f(sacc[it][1] - m_lane);
            float p2 = exp2f(sacc[it][2] - m_lane);
            float p3 = exp2f(sacc[it][3] - m_lane);
            uint2 u;
            u.x = p2u(p0, p1);
            u.y = p2u(p2, p3);
            *(uint2*)&pps[j * 68 + it * 16 + quad * 4] = u;
        }

        asm volatile("s_waitcnt lgkmcnt(0)" ::: "memory");
        __builtin_amdgcn_s_barrier();
        __builtin_amdgcn_sched_barrier(0);

        __builtin_amdgcn_s_setprio(1);
#pragma unroll
        for (int cc = 0; cc < 2; cc++) {
            f16x8 afr[2], bfr[4];
#pragma unroll
            for (int t = 0; t < 2; t++)
                afr[t] = *(const f16x8*)&vbuf[cur][((w * 2 + t) * 2 + cc) * 512 + lane8];
#pragma unroll
            for (int t = 0; t < 4; t++)
                bfr[t] = *(const f16x8*)&pps[(t * 16 + ln15) * 68 + cc * 32 + quad * 8];
#pragma unroll
            for (int a = 0; a < 2; a++)
#pragma unroll
                for (int bb = 0; bb < 4; bb++)
                    oacc[a][bb] = __builtin_amdgcn_mfma_f32_16x16x32_f16(afr[a], bfr[bb], oacc[a][bb], 0, 0, 0);
        }
        __builtin_amdgcn_s_setprio(0);

        __syncthreads();
        cur ^= 1;
    }

#pragma unroll
    for (int a = 0; a < 2; a++)
#pragma unroll
        for (int r = 0; r < 4; r++) {
            const int co = co0 + wco + a * 16 + quad * 4 + r;
            float* ob = out + ((size_t)b * C_DIM + co) * L_DIM + j0;
#pragma unroll
            for (int bb = 0; bb < 4; bb++)
                ob[bb * 16 + ln15] = oacc[a][bb][r] * inv[bb];
        }
}

// ---------------------------------------------------------------------------
extern "C" void kernel_launch(void* const* d_in, const int* in_sizes, int n_in,
                              void* d_out, int out_size, void* d_ws, size_t ws_size,
                              hipStream_t stream) {
    const float* x     = (const float*)d_in[0];
    const float* Wq    = (const float*)d_in[1];
    const float* Wk    = (const float*)d_in[2];
    const float* Wv    = (const float*)d_in[3];
    const float* gamma = (const float*)d_in[4];
    float* out = (float*)d_out;

    unsigned short* ws_h = (unsigned short*)d_ws;
    unsigned short* qT = ws_h;                        // 8*2048*64   = 1,048,576
    unsigned short* kT = qT + 1048576;
    unsigned short* vB = kT + 1048576;                // 8*512*2048  = 8,388,608
    unsigned short* xT = vB + 8388608;                // 8*2048*512  = 8,388,608
    unsigned short* Wh = xT + 8388608;                // 3*640*512   = 983,040
    unsigned short* Pm = Wh + 983040;                 // 8*2048*2048 = 33,554,432
    // stats reuse the xT region (dead after conv_all): 2 * 8*8*2048 floats = 1 MB
    float* pstat = (float*)xT;

    const size_t need_bytes = ((size_t)19857408 + 33554432) * 2;  // ~107 MB

    prep_w  <<<3840, 256, 0, stream>>>(Wq, Wk, Wv, Wh);
    prep_x  <<<dim3(32, 8, 8), 256, 0, stream>>>(x, xT);
    conv_all<<<dim3(16, 10, 8), 256, 0, stream>>>(Wh, xT, qT, kT, vB);
    stat_k  <<<dim3(8, 32, 8), 256, 0, stream>>>(qT, kT, pstat);
    if (ws_size >= need_bytes) {
        sc_p <<<dim3(8, 32, 8), 256, 0, stream>>>(qT, kT, pstat, Pm);
        pv3  <<<dim3(16, 4, 8), 512, 0, stream>>>(vB, Pm, pstat, gamma, out);
    } else {
        pv2  <<<dim3(32, 4, 8), 256, 0, stream>>>(qT, kT, vB, pstat, gamma, out);
    }
}